// Round 5
// baseline (601.743 us; speedup 1.0000x reference)
//
#include <hip/hip_runtime.h>
#include <math.h>

// SwarmSetEquivariantTorso — bf16 MFMA, act-fragment-reuse block GEMMs.
// Block = 256 threads / 4 waves / 12 tokens (60 slot rows = 4 M-tiles).
// GEMM restructure vs prev: loop order mt->kt->ln with NTPW accumulators,
// fused multi-weight calls (QKV share one act read; PK/PV likewise), and
// M-split x N-split for 60-row layers (each wave: 2 N-tiles x 2 M-tiles).
// Act ds_read_b128 count: 218 -> 72 per wave (LDS pipe was the bottleneck:
// MfmaUtil 8.8 / VALUBusy 47 / HBM 1.9% — GEMM act reads alone were ~50%
// of all CU cycles on the LDS pipe). Weight frags re-read from L2 (idle).
// Glue: parallel LN/l3 (2-shuffle reductions), fast exact gelu, qp precomputed.

#define DOBS 198
#define NEG_INF_F (-3.402823466e38f)

typedef __bf16 v8bf __attribute__((ext_vector_type(8)));
typedef __bf16 v4bf __attribute__((ext_vector_type(4)));
typedef float  v4f  __attribute__((ext_vector_type(4)));

struct P {
  const float *obs,*tok_w,*tok_b,*ln1_s,*ln1_b,
    *a1_qw,*a1_qb,*a1_kw,*a1_kb,*a1_vw,*a1_vb,*a1_ow,*a1_ob,
    *ln2_s,*ln2_b,*m1_w,*m1_b,*m2_w,*m2_b,*m3_w,*m3_b,
    *e1_w,*e1_b,*e2_w,*e2_b,*e3_w,*e3_b,
    *l1_w,*l1_b,*l2_w,*l2_b,*l3_w,*l3_b,
    *seed,*p_qw,*p_qb,*p_kw,*p_kb,*p_vw,*p_vb,*p_ow,*p_ob,
    *pr_w,*pr_b,*h1_w,*h1_b,*h2_w,*h2_b,*h3_w,*h3_b;
  float* out;
};
static_assert(sizeof(P) == 51*sizeof(void*), "P layout");

// ws bf16 weight image, W_t[n][k] per matrix (element offsets)
#define W_A1Q 0
#define W_A1K 4096
#define W_A1V 8192
#define W_A1O 12288
#define W_M1  16384
#define W_M2  24576
#define W_M3  40960
#define W_E1  49152
#define W_E2  53248
#define W_E3  69632
#define W_L1  77824
#define W_L2  94208
#define W_PK  110592
#define W_PV  114688
#define W_PO  118784
#define W_H1  122880
#define W_H2  143360
#define W_H3  159744
#define W_END 176128
#define W_QP  176128   // + 64 f32 (pooling query, precomputed)

__global__ __launch_bounds__(256)
void prep_w(P a, __bf16* ws)
{
  if (blockIdx.x == 172){
    int t = threadIdx.x;
    if (t < 64){
      float acc = a.p_qb[t];
      for (int k=0;k<64;k++) acc += a.seed[k]*a.p_qw[k*64+t];
      ((float*)(ws + W_QP))[t] = acc;
    }
    return;
  }
  const float* srcs[18] = {a.a1_qw,a.a1_kw,a.a1_vw,a.a1_ow,a.m1_w,a.m2_w,a.m3_w,
                           a.e1_w,a.e2_w,a.e3_w,a.l1_w,a.l2_w,a.p_kw,a.p_vw,a.p_ow,
                           a.h1_w,a.h2_w,a.h3_w};
  const int Ks[18]   = {64,64,64,64,64,128,128,32,128,128,128,128,64,64,64,160,128,128};
  const int Ns[18]   = {64,64,64,64,128,128,64,128,128,64,128,128,64,64,64,128,128,128};
  const int offs[18] = {W_A1Q,W_A1K,W_A1V,W_A1O,W_M1,W_M2,W_M3,W_E1,W_E2,W_E3,
                        W_L1,W_L2,W_PK,W_PV,W_PO,W_H1,W_H2,W_H3};
  __shared__ float tile[32][33];
  int b = blockIdx.x, m = 0, acc = 0;
  for (; m < 18; m++){
    int t = (Ks[m]/32)*(Ns[m]/32);
    if (b < acc + t) break;
    acc += t;
  }
  int lt = b - acc, K = Ks[m], N = Ns[m];
  int ntile = N/32, kt = lt/ntile, nt = lt%ntile;
  int tx = threadIdx.x & 31, ty = threadIdx.x >> 5;
  const float* S = srcs[m];
  #pragma unroll
  for (int rr=0; rr<32; rr+=8)
    tile[ty+rr][tx] = S[(size_t)(kt*32+ty+rr)*N + nt*32+tx];
  __syncthreads();
  __bf16* D = ws + offs[m];
  #pragma unroll
  for (int rr=0; rr<32; rr+=8)
    D[(size_t)(nt*32+ty+rr)*K + kt*32+tx] = (__bf16)tile[tx][ty+rr];
}

// gelu(x) = x * sigmoid(2t),  t = 0.79788456(x + 0.044715 x^3)  (exact tanh form)
__device__ __forceinline__ float gelu_f(float x){
  float t = x * fmaf(0.0356774081f, x*x, 0.7978845608f);
  float u = __builtin_amdgcn_exp2f(-2.885390082f * t);
  return x * __builtin_amdgcn_rcpf(1.0f + u);
}

__device__ __forceinline__ void load16f(const __bf16* p, float* f){
  v8bf a = *(const v8bf*)p, b = *(const v8bf*)(p+8);
  #pragma unroll
  for (int i=0;i<8;i++){ f[i]=(float)a[i]; f[8+i]=(float)b[i]; }
}

// Act-reuse block GEMM: D[60+pad x N] = act @ W + bias, NW fused weight
// matrices sharing the act reads.
//   MSPL: M-split factor. Waves form a (MSPL x NWN) grid, NWN = 4/MSPL.
//   Wave (mg,ng): owns M-tiles mg*MT/MSPL.., N-tiles ng*NTPW..+NTPW-1 of
//   each of the NW matrices. Per (mt,kt): ONE act ds_read_b128 feeds
//   NW*NTPW MFMAs (act-fragment reuse — LDS pipe relief). Weight frags
//   (global, L2-hot ws) preloaded once per call.
// epi(w, wbase, mt, ar, c): matrix w, D rows mt*16+ar, cols wbase..wbase+3.
template<int KT,int MT,int NTPW,int MSPL,int NW,typename LA,typename E>
__device__ __forceinline__ void gemmNS(LA la, const __bf16* const* Ws,
    const float* const* bs, int wv, int lane, E epi)
{
  static_assert(MT % MSPL == 0, "MT % MSPL");
  const int ar = lane&15, quad = lane>>4;
  constexpr int NWN = 4/MSPL;
  constexpr int SH  = (NWN==4)?2:((NWN==2)?1:0);
  constexpr int MTW = MT/MSPL;
  const int ng = wv & (NWN-1), mg = wv >> SH;
  v8bf  wf[NW][NTPW][KT];
  float4 b4[NW][NTPW];
  #pragma unroll
  for (int w=0; w<NW; w++)
  #pragma unroll
  for (int ln=0; ln<NTPW; ln++){
    const int wt = ng*NTPW + ln;
    const __bf16* wp = Ws[w] + (size_t)(wt*16+ar)*(KT*32) + quad*8;
    #pragma unroll
    for (int kt=0;kt<KT;kt++) wf[w][ln][kt] = *(const v8bf*)(wp + kt*32);
    b4[w][ln] = *(const float4*)(bs[w] + wt*16 + quad*4);
  }
  #pragma unroll
  for (int mi=0; mi<MTW; mi++){
    const int mt = mg*MTW + mi;
    v4f c[NW][NTPW];
    #pragma unroll
    for (int w=0;w<NW;w++)
    #pragma unroll
    for (int ln=0;ln<NTPW;ln++){
      c[w][ln][0]=b4[w][ln].x; c[w][ln][1]=b4[w][ln].y;
      c[w][ln][2]=b4[w][ln].z; c[w][ln][3]=b4[w][ln].w;
    }
    #pragma unroll
    for (int kt=0;kt<KT;kt++){
      v8bf av = la(mt,kt,ar,quad);
      #pragma unroll
      for (int w=0;w<NW;w++)
      #pragma unroll
      for (int ln=0;ln<NTPW;ln++)
        c[w][ln] = __builtin_amdgcn_mfma_f32_16x16x32_bf16(wf[w][ln][kt], av, c[w][ln], 0,0,0);
    }
    #pragma unroll
    for (int w=0;w<NW;w++)
    #pragma unroll
    for (int ln=0;ln<NTPW;ln++)
      epi(w, (ng*NTPW+ln)*16 + quad*4, mt, ar, c[w][ln]);
  }
}

// Single-matrix convenience wrapper (keeps old epi signature).
template<int KT,int MT,int NTPW,int MSPL,typename LA,typename E>
__device__ __forceinline__ void gemm1(LA la, const __bf16* W, const float* b,
    int wv, int lane, E epi)
{
  const __bf16* Ws[1] = {W}; const float* bs[1] = {b};
  gemmNS<KT,MT,NTPW,MSPL,1>(la, Ws, bs, wv, lane,
    [&](int, int wb,int mt,int r,v4f c){ epi(wb,mt,r,c); });
}

// LDS map (bytes), total 53120 <= 53248 (proven 3 blocks/CU):
//  Ab   @0      bf16[64][136] 17408  (early: Df f32[12][32])
//  Bb   @17408  bf16[64][136] 17408  (early: TOKIN f32[60][12])
//  Tk   @34816  bf16[64][72]   9216  (early: OBSf f32[12][120]; late: Po bf16[12][64])
//  Pe   @44032  bf16[16][64]   2048
//  Eg   @46080  bf16[16][40]   1280
//  Ru   @47360  bf16[12][30]    736
//  mfb  @48096  bf16[64]        128
//  msfb @48224  bf16[64]        128
//  many @48352  f32[16]          64
//  lga  @48416  f32[64]         256
//  ECX  @48672  bf16[16][64]   2048  (late: pattn f32[12][20])
//  ATTb @50720  bf16[12][100]  2400  (late: Cc bf16[16][64])
__global__ __launch_bounds__(256,3)
void swarm_mfma(P a, const __bf16* __restrict__ ws, int ntok)
{
  __shared__ char smem[53120] __attribute__((aligned(16)));
  __bf16* Ab   = (__bf16*)(smem);
  __bf16* Bb   = (__bf16*)(smem+17408);
  float*  TOKIN= (float*) (smem+17408);
  __bf16* Tk   = (__bf16*)(smem+34816);
  float*  OBSf = (float*) (smem+34816);
  __bf16* Po   = (__bf16*)(smem+34816);
  __bf16* Pe   = (__bf16*)(smem+44032);
  __bf16* Eg   = (__bf16*)(smem+46080);
  __bf16* Ru   = (__bf16*)(smem+47360);
  __bf16* mfb  = (__bf16*)(smem+48096);
  __bf16* msfb = (__bf16*)(smem+48224);
  float*  many = (float*) (smem+48352);
  float*  lga  = (float*) (smem+48416);
  __bf16* ECX  = (__bf16*)(smem+48672);
  float*  pattn= (float*) (smem+48672);
  __bf16* ATTb = (__bf16*)(smem+50720);
  __bf16* Cc   = (__bf16*)(smem+50720);

  const int lane = threadIdx.x & 63;
  const int wv   = threadIdx.x >> 6;
  const int ar   = lane & 15, quad = lane >> 4;
  const long blkT0 = (long)blockIdx.x*12;

  // ================= setup (wave-local tokens 3wv..3wv+2) =================
  for (int it=lane; it<3*117; it+=64){
    int tg=it/117, c=it-tg*117;
    long gt = blkT0 + 3*wv + tg; if (gt>ntok-1) gt=ntok-1;
    OBSf[(3*wv+tg)*120+c] = a.obs[gt*DOBS+c];
  }
  float* Df = (float*)Ab;
  for (int it=lane; it<75; it+=64){
    int tg=it/25, p=it-tg*25, i=p/5, j=p-i*5;
    const float* ob = OBSf + (3*wv+tg)*120 + 32;
    float d2=0.f;
    #pragma unroll
    for (int d=0;d<3;d++){
      float ri=ob[15*i+d]; ri = isfinite(ri)?ri:0.f;
      float rj=ob[15*j+d]; rj = isfinite(rj)?rj:0.f;
      float df=ri-rj; d2 += df*df;
    }
    Df[(3*wv+tg)*32+p]=sqrtf(d2);
  }
  if (lane<15){
    int T=3*wv+lane/5, s=lane%5;
    const float* b = OBSf + T*120 + 32 + 15*s;
    mfb[15*wv+lane] = (__bf16)((fabsf(b[0])>1e-6f||fabsf(b[1])>1e-6f||fabsf(b[2])>1e-6f)?1.f:0.f);
  }
  if (wv==0 && lane>=60){ mfb[lane]=(__bf16)0.f; msfb[lane]=(__bf16)0.f; }
  if (wv==0 && lane>=12 && lane<16) many[lane]=0.f;
  if (lane<3){
    int T=3*wv+lane;
    float any = (float)mfb[T*5]+(float)mfb[T*5+1]+(float)mfb[T*5+2]+(float)mfb[T*5+3]+(float)mfb[T*5+4];
    float anyf = (any>0.f)?1.f:0.f; many[T]=anyf;
    #pragma unroll
    for (int i=0;i<5;i++) msfb[T*5+i] = (anyf>0.f)? mfb[T*5+i] : (__bf16)((i==0)?1.f:0.f);
  }
  if (lane<15){
    int T=3*wv+lane/5, i=lane%5, R=15*wv+lane;
    float dmin=1e9f,dsum=0.f,cnt=0.f;
    #pragma unroll
    for (int j=0;j<5;j++){
      if (j!=i && (float)mfb[T*5+i]>0.5f && (float)mfb[T*5+j]>0.5f){
        float dd=Df[T*32+i*5+j];
        dmin=fminf(dmin,dd); dsum+=dd; cnt+=1.f;
      }
    }
    TOKIN[R*12+10]=dmin;
    TOKIN[R*12+11]=(cnt>0.f)? dsum/(cnt+1e-9f) : 0.f;
  }
  for (int it=lane; it<150; it+=64){
    int tg=it/50, q=it-tg*50, s=q/10, c=q-s*10;
    int T=3*wv+tg;
    const float* b = OBSf + T*120 + 32 + 15*s;
    float v;
    if (c<4)        v=b[11+c];
    else if (c==4)  v=b[9];
    else if (c==5)  v=b[10];
    else if (c<9)   v=b[6+(c-6)];
    else { float a0=b[6],a1=b[7],a2=b[8]; v=sqrtf(a0*a0+a1*a1+a2*a2); }
    TOKIN[(T*5+s)*12+c]=v;
  }
  for (int it=lane; it<96; it+=64){
    int tg=it>>5, c=it&31;
    Eg[(3*wv+tg)*40+c] = (__bf16)OBSf[(3*wv+tg)*120+c];
  }
  for (int it=lane; it<90; it+=64){
    int tg=it/30, c=it-tg*30;
    Ru[(3*wv+tg)*30+c] = (__bf16)OBSf[(3*wv+tg)*120+32+15*(c/6)+(c%6)];
  }
  for (int it=lane; it<192; it+=64){
    int tg=it>>6, c=it&63;
    float acc = a.pr_b[c];
    #pragma unroll
    for (int k=0;k<10;k++) acc += OBSf[(3*wv+tg)*120+107+k]*a.pr_w[k*64+c];
    Pe[(3*wv+tg)*64+c] = (__bf16)gelu_f(acc);
  }
  __syncthreads();   // S0: OBSf/Df/TOKIN producers done; Tk writes may begin

  // ---- P3: tok embed (fp32 K=12) -> Tk rows 15wv..15wv+14; then ln1 -> Ab ----
  {
    float w0[12];
    #pragma unroll
    for (int k=0;k<12;k++) w0[k] = a.tok_w[k*64+lane];
    float tb = a.tok_b[lane];
    for (int r=0;r<15;r++){
      int R = 15*wv + r;
      const float4* tin = (const float4*)(TOKIN + R*12);
      float4 x0 = tin[0], x1 = tin[1], x2 = tin[2];
      float acc = tb;
      acc=fmaf(x0.x,w0[0],acc); acc=fmaf(x0.y,w0[1],acc);
      acc=fmaf(x0.z,w0[2],acc); acc=fmaf(x0.w,w0[3],acc);
      acc=fmaf(x1.x,w0[4],acc); acc=fmaf(x1.y,w0[5],acc);
      acc=fmaf(x1.z,w0[6],acc); acc=fmaf(x1.w,w0[7],acc);
      acc=fmaf(x2.x,w0[8],acc); acc=fmaf(x2.y,w0[9],acc);
      acc=fmaf(x2.z,w0[10],acc); acc=fmaf(x2.w,w0[11],acc);
      Tk[R*72+lane] = (__bf16)(gelu_f(acc)*(float)mfb[R]);
    }
  }
  if (ar<15){   // ln1, own rows (shuffles stay within same-ar groups)
    int R = 15*wv + ar;
    float x[16]; load16f(Tk + R*72 + quad*16, x);
    float s=0.f;
    #pragma unroll
    for (int i=0;i<16;i++) s += x[i];
    s += __shfl_xor(s,16,64); s += __shfl_xor(s,32,64);
    float m = s*(1.f/64.f), q=0.f;
    #pragma unroll
    for (int i=0;i<16;i++){ float d=x[i]-m; q=fmaf(d,d,q); }
    q += __shfl_xor(q,16,64); q += __shfl_xor(q,32,64);
    float rs = __builtin_amdgcn_rsqf(q*(1.f/64.f)+1e-6f);
    v8bf o0,o1;
    #pragma unroll
    for (int i=0;i<8;i++){
      o0[i]=(__bf16)((x[i]  -m)*rs*a.ln1_s[quad*16+i]  +a.ln1_b[quad*16+i]);
      o1[i]=(__bf16)((x[8+i]-m)*rs*a.ln1_s[quad*16+8+i]+a.ln1_b[quad*16+8+i]);
    }
    *(v8bf*)(Ab+R*136+quad*16)=o0; *(v8bf*)(Ab+R*136+quad*16+8)=o1;
  }
  __syncthreads();   // S1

  auto actAb = [&](int mt,int kt,int r,int q){ return *(const v8bf*)(Ab + (size_t)(mt*16+r)*136 + q*8 + kt*32); };
  auto actBb = [&](int mt,int kt,int r,int q){ return *(const v8bf*)(Bb + (size_t)(mt*16+r)*136 + q*8 + kt*32); };
  auto actTk = [&](int mt,int kt,int r,int q){ return *(const v8bf*)(Tk + (size_t)(mt*16+r)*72  + q*8 + kt*32); };

  // ---- QKV fused (one act read feeds K,V,Q): K -> Bb[:,64:], V -> Ab[:,64:],
  //      Q -> Bb[:,0:64] ----
  {
    const __bf16* Ws[3] = {ws+W_A1K, ws+W_A1V, ws+W_A1Q};
    const float*  bs[3] = {a.a1_kb, a.a1_vb, a.a1_qb};
    gemmNS<2,4,2,2,3>(actAb, Ws, bs, wv, lane,
      [&](int w,int wb,int mt,int r,v4f c){ v4bf o;
        #pragma unroll
        for (int k=0;k<4;k++) o[k]=(__bf16)c[k];
        __bf16* d = (w==0)? &Bb[(mt*16+r)*136+64+wb]
                 : (w==1)? &Ab[(mt*16+r)*136+64+wb]
                         : &Bb[(mt*16+r)*136+wb];
        *(v4bf*)d = o; });
  }
  __syncthreads();   // S2

  // ---- attn weights + attn@V (wave-local tokens) ----
  if (lane<60){
    int tg=lane/20, rem=lane-tg*20, h=rem/5, i=rem-h*5;
    int T=3*wv+tg;
    bool mi = (float)msfb[T*5+i]>0.5f;
    float qv[16]; load16f(&Bb[(T*5+i)*136 + h*16], qv);
    float lgv[5], mx=NEG_INF_F;
    #pragma unroll
    for (int j=0;j<5;j++){
      float kk[16]; load16f(&Bb[(T*5+j)*136 + 64 + h*16], kk);
      float d=0.f;
      #pragma unroll
      for (int dd=0;dd<16;dd++) d += qv[dd]*kk[dd];
      bool mj = (float)msfb[T*5+j]>0.5f;
      lgv[j] = (mi&&mj)? d*0.25f : NEG_INF_F;
      mx = fmaxf(mx,lgv[j]);
    }
    float sum=0.f, ex[5];
    #pragma unroll
    for (int j=0;j<5;j++){ ex[j]=__expf(lgv[j]-mx); sum+=ex[j]; }
    float inv=1.0f/sum;
    #pragma unroll
    for (int j=0;j<5;j++) ATTb[T*100+(h*5+i)*5+j]=(__bf16)(ex[j]*inv);
  }
  {
    int h = lane>>4;
    #pragma unroll
    for (int tg=0; tg<3; tg++){
      int T=3*wv+tg;
      float v5[5];
      #pragma unroll
      for (int j=0;j<5;j++) v5[j] = (float)Ab[(T*5+j)*136+64+lane];
      #pragma unroll
      for (int i=0;i<5;i++){
        float o=0.f;
        #pragma unroll
        for (int j=0;j<5;j++) o += (float)ATTb[T*100+(h*5+i)*5+j]*v5[j];
        Ab[(T*5+i)*136+lane]=(__bf16)o;
      }
    }
  }
  __syncthreads();   // S3

  // ---- o-proj + residual -> Tk (col-slices) ----
  gemm1<2,4,2,2>(actAb, ws+W_A1O, a.a1_ob, wv, lane,
    [&](int wb,int mt,int r,v4f c){
      int R=mt*16+r; float mm=(float)mfb[R];
      v4bf old=*(const v4bf*)&Tk[R*72+wb]; v4bf o;
      #pragma unroll
      for (int k=0;k<4;k++) o[k]=(__bf16)((float)old[k]+c[k]*mm);
      *(v4bf*)&Tk[R*72+wb]=o; });
  __syncthreads();   // S4

  // ---- ln2 -> Ab[:,0:64] (own rows) ----
  if (ar<15){
    int R = 15*wv + ar;
    float x[16]; load16f(Tk + R*72 + quad*16, x);
    float s=0.f;
    #pragma unroll
    for (int i=0;i<16;i++) s += x[i];
    s += __shfl_xor(s,16,64); s += __shfl_xor(s,32,64);
    float m = s*(1.f/64.f), q=0.f;
    #pragma unroll
    for (int i=0;i<16;i++){ float d=x[i]-m; q=fmaf(d,d,q); }
    q += __shfl_xor(q,16,64); q += __shfl_xor(q,32,64);
    float rs = __builtin_amdgcn_rsqf(q*(1.f/64.f)+1e-6f);
    v8bf o0,o1;
    #pragma unroll
    for (int i=0;i<8;i++){
      o0[i]=(__bf16)((x[i]  -m)*rs*a.ln2_s[quad*16+i]  +a.ln2_b[quad*16+i]);
      o1[i]=(__bf16)((x[8+i]-m)*rs*a.ln2_s[quad*16+8+i]+a.ln2_b[quad*16+8+i]);
    }
    *(v8bf*)(Ab+R*136+quad*16)=o0; *(v8bf*)(Ab+R*136+quad*16+8)=o1;
  }
  __syncthreads();   // S5

  // ---- m1 -> Bb[:,0:128] ----
  gemm1<2,4,4,2>(actAb, ws+W_M1, a.m1_b, wv, lane,
    [&](int wb,int mt,int r,v4f c){ v4bf o;
      #pragma unroll
      for (int k=0;k<4;k++) o[k]=(__bf16)gelu_f(c[k]);
      *(v4bf*)&Bb[(mt*16+r)*136+wb]=o; });
  __syncthreads();   // S6
  // ---- m2 -> Ab[:,0:128] ----
  gemm1<4,4,4,2>(actBb, ws+W_M2, a.m2_b, wv, lane,
    [&](int wb,int mt,int r,v4f c){ v4bf o;
      #pragma unroll
      for (int k=0;k<4;k++) o[k]=(__bf16)gelu_f(c[k]);
      *(v4bf*)&Ab[(mt*16+r)*136+wb]=o; });
  __syncthreads();   // S7
  // ---- m3 -> Tk (resid*mask) ; e1 (token-level) -> Bb rows 0..15 ----
  gemm1<4,4,2,2>(actAb, ws+W_M3, a.m3_b, wv, lane,
    [&](int wb,int mt,int r,v4f c){
      int R=mt*16+r; float mm=(float)mfb[R];
      v4bf old=*(const v4bf*)&Tk[R*72+wb]; v4bf o;
      #pragma unroll
      for (int k=0;k<4;k++) o[k]=(__bf16)(((float)old[k]+c[k]*mm)*mm);
      *(v4bf*)&Tk[R*72+wb]=o; });
  gemm1<1,1,2,1>([&](int,int,int r,int q){ return *(const v8bf*)(Eg + (size_t)r*40 + q*8); },
    ws+W_E1, a.e1_b, wv, lane,
    [&](int wb,int mt,int r,v4f c){ v4bf o;
      #pragma unroll
      for (int k=0;k<4;k++) o[k]=(__bf16)gelu_f(c[k]);
      *(v4bf*)&Bb[r*136+wb]=o; });
  __syncthreads();   // S8
  // ---- e2 -> Ab rows 0..15 ----
  gemm1<4,1,2,1>(actBb, ws+W_E2, a.e2_b, wv, lane,
    [&](int wb,int mt,int r,v4f c){ v4bf o;
      #pragma unroll
      for (int k=0;k<4;k++) o[k]=(__bf16)gelu_f(c[k]);
      *(v4bf*)&Ab[r*136+wb]=o; });
  __syncthreads();   // S9
  // ---- e3 -> ECX rows 0..15 ----
  gemm1<4,1,1,1>(actAb, ws+W_E3, a.e3_b, wv, lane,
    [&](int wb,int mt,int r,v4f c){ v4bf o;
      #pragma unroll
      for (int k=0;k<4;k++) o[k]=(__bf16)c[k];
      *(v4bf*)&ECX[r*64+wb]=o; });
  __syncthreads();   // S10
  // ---- l1 (act = [Tk | ECX(token)]) -> Bb[:,0:128] ----
  gemm1<4,4,4,2>([&](int mt,int kt,int r,int q){
      int R=mt*16+r;
      return (kt<2) ? *(const v8bf*)(Tk + (size_t)R*72 + q*8 + kt*32)
                    : *(const v8bf*)(ECX + (size_t)((R*205)>>10)*64 + q*8 + (kt-2)*32); },
    ws+W_L1, a.l1_b, wv, lane,
    [&](int wb,int mt,int r,v4f c){ v4bf o;
      #pragma unroll
      for (int k=0;k<4;k++) o[k]=(__bf16)gelu_f(c[k]);
      *(v4bf*)&Bb[(mt*16+r)*136+wb]=o; });
  __syncthreads();   // S11
  // ---- l2 -> Ab[:,0:128] ----
  gemm1<4,4,4,2>(actBb, ws+W_L2, a.l2_b, wv, lane,
    [&](int wb,int mt,int r,v4f c){ v4bf o;
      #pragma unroll
      for (int k=0;k<4;k++) o[k]=(__bf16)gelu_f(c[k]);
      *(v4bf*)&Ab[(mt*16+r)*136+wb]=o; });
  __syncthreads();   // S12

  // ---- l3 (own rows) + alpha + v_r/v_u ; kp/vp fused -> Bb ----
  if (ar<15){
    int R = 15*wv + ar;
    float x[16], y[16];
    load16f(&Ab[R*136 + quad*32], x);
    load16f(&Ab[R*136 + quad*32 + 16], y);
    const float* w = a.l3_w + quad*32;
    float p = 0.f;
    #pragma unroll
    for (int i=0;i<16;i++) p = fmaf(x[i], w[i], p);
    #pragma unroll
    for (int i=0;i<16;i++) p = fmaf(y[i], w[16+i], p);
    p += __shfl_xor(p,16,64); p += __shfl_xor(p,32,64);
    if (quad==0) lga[R] = p + a.l3_b[0];
  }
  {
    const __bf16* Ws[2] = {ws+W_PK, ws+W_PV};
    const float*  bs[2] = {a.p_kb, a.p_vb};
    gemmNS<2,4,2,2,2>(actTk, Ws, bs, wv, lane,
      [&](int w,int wb,int mt,int r,v4f c){ v4bf o;
        #pragma unroll
        for (int k=0;k<4;k++) o[k]=(__bf16)c[k];
        *(v4bf*)&Bb[(mt*16+r)*136 + (w?64:0) + wb] = o; });
  }
  if (lane<3){
    int T=3*wv+lane;
    float ml[5], mx=-1e9f;
    #pragma unroll
    for (int i=0;i<5;i++){ ml[i]=((float)mfb[T*5+i]>0.5f)? lga[T*5+i] : -1e9f; mx=fmaxf(mx,ml[i]); }
    float den=0.f, e[5];
    #pragma unroll
    for (int i=0;i<5;i++){ e[i]=__expf(ml[i]-mx)*(float)mfb[T*5+i]; den+=e[i]; }
    float inv=1.0f/(den+1e-9f);
    #pragma unroll
    for (int i=0;i<5;i++) lga[T*5+i]=e[i]*inv;
  }
  if (lane<18){
    int tg=lane/6, c=lane-tg*6;
    int T=3*wv+tg;
    float v=0.f;
    #pragma unroll
    for (int i=0;i<5;i++) v += lga[T*5+i]*(float)Ru[T*30+i*6+c];
    long tk = blkT0 + T;
    if (tk<ntok) a.out[tk*134+128+c]=v;
  }
  __syncthreads();   // S13

  // ---- pooling attn + pooled-o (wave-local tokens) ----
  if (lane<12){
    const float* qg = (const float*)(ws + W_QP);
    int tg=lane>>2, h=lane&3;
    int T=3*wv+tg;
    float qv[16];
    #pragma unroll
    for (int dd=0;dd<16;dd++) qv[dd]=qg[h*16+dd];
    float lgv[5], mx=NEG_INF_F;
    #pragma unroll
    for (int j=0;j<5;j++){
      float kk[16]; load16f(&Bb[(T*5+j)*136 + h*16], kk);
      float d=0.f;
      #pragma unroll
      for (int dd=0;dd<16;dd++) d += qv[dd]*kk[dd];
      lgv[j] = ((float)msfb[T*5+j]>0.5f)? d*0.25f : NEG_INF_F;
      mx = fmaxf(mx,lgv[j]);
    }
    float sum=0.f, ex[5];
    #pragma unroll
    for (int j=0;j<5;j++){ ex[j]=__expf(lgv[j]-mx); sum+=ex[j]; }
    float inv=1.0f/sum;
    #pragma unroll
    for (int j=0;j<5;j++) pattn[T*20+h*5+j]=ex[j]*inv;
  }
  for (int it=lane; it<192; it+=64){
    int tg=it>>6, c=it&63, h=c>>4;
    int T=3*wv+tg;
    float o=0.f;
    #pragma unroll
    for (int j=0;j<5;j++)
      o += pattn[T*20+h*5+j]*(float)Bb[(T*5+j)*136+64+c];
    Po[T*64+c]=(__bf16)o;
  }
  __syncthreads();   // S14

  // ---- p_ow -> Cc (x many) ----
  gemm1<2,1,1,1>([&](int,int kt,int r,int q){ return *(const v8bf*)(Po + (size_t)r*64 + q*8 + kt*32); },
    ws+W_PO, a.p_ob, wv, lane,
    [&](int wb,int mt,int r,v4f c){
      float mm = many[r];
      v4bf o;
      #pragma unroll
      for (int k=0;k<4;k++) o[k]=(__bf16)(c[k]*mm);
      *(v4bf*)&Cc[r*64+wb]=o; });
  __syncthreads();   // S15

  // ---- h1 (act = [Eg | Cc | Pe], K=160) -> Bb rows 0..15 ----
  gemm1<5,1,2,1>([&](int,int kt,int r,int q){
      if (kt==0) return *(const v8bf*)(Eg + (size_t)r*40 + q*8);
      if (kt<3)  return *(const v8bf*)(Cc + (size_t)r*64 + q*8 + (kt-1)*32);
      return *(const v8bf*)(Pe + (size_t)r*64 + q*8 + (kt-3)*32); },
    ws+W_H1, a.h1_b, wv, lane,
    [&](int wb,int mt,int r,v4f c){ v4bf o;
      #pragma unroll
      for (int k=0;k<4;k++) o[k]=(__bf16)gelu_f(c[k]);
      *(v4bf*)&Bb[r*136+wb]=o; });
  __syncthreads();   // S16
  // ---- h2 -> Ab rows 0..15 ----
  gemm1<4,1,2,1>(actBb, ws+W_H2, a.h2_b, wv, lane,
    [&](int wb,int mt,int r,v4f c){ v4bf o;
      #pragma unroll
      for (int k=0;k<4;k++) o[k]=(__bf16)gelu_f(c[k]);
      *(v4bf*)&Ab[r*136+wb]=o; });
  __syncthreads();   // S17
  // ---- h3 -> out ----
  gemm1<4,1,2,1>(actAb, ws+W_H3, a.h3_b, wv, lane,
    [&](int wb,int mt,int r,v4f c){
      long tk = blkT0 + r;
      if (r<12 && tk<ntok){
        float2* o2 = (float2*)&a.out[tk*134 + wb];
        o2[0] = make_float2(c[0], c[1]);
        o2[1] = make_float2(c[2], c[3]);
      } });
}

extern "C" void kernel_launch(void* const* d_in, const int* in_sizes, int n_in,
                              void* d_out, int out_size, void* d_ws, size_t ws_size,
                              hipStream_t stream)
{
  P a;
  const float** pp = reinterpret_cast<const float**>(&a);
  for (int i=0;i<50;i++) pp[i] = reinterpret_cast<const float*>(d_in[i]);
  a.out = reinterpret_cast<float*>(d_out);
  int ntok = in_sizes[0] / DOBS;   // 65536

  __bf16* ws = reinterpret_cast<__bf16*>(d_ws);
  hipLaunchKernelGGL(prep_w, dim3(173), dim3(256), 0, stream, a, ws);
  hipLaunchKernelGGL(swarm_mfma, dim3((ntok+11)/12), dim3(256), 0, stream, a, ws, ntok);
}

// Round 7
// 568.567 us; speedup vs baseline: 1.0584x; 1.0584x over previous
//
#include <hip/hip_runtime.h>
#include <math.h>

// SwarmSetEquivariantTorso — bf16 MFMA, N-split block GEMMs, 4 blocks/CU.
// ROUND-5 POST-MORTEM: act-fragment-reuse restructure REGRESSED 375->463us
// (conflicts dropped 28.6M->18.3M as predicted, but batched global weight
// loads + VGPR 84 put vmcnt stalls on the critical path; VALUBusy fell
// 47->38 = waves idling). Reverted to the round-0 GEMM structure.
// THIS VERSION: same per-layer structure as the 375us kernel, but
// 8 tokens/block (40 slot rows = 3 M-tiles) so LDS = 40736B <= 40960
// -> 4 blocks/CU (16 waves, was 3/12). Both profiles show ~44-55% idle
// wave time with glue-VALU ~47% and MFMA ~9%; occupancy is the fillable
// lever. LDS shaves: Eg stride 40->32, Cc overlays ECX, pattn overlays
// ATTb. Glue: parallel LN/l3, fast exact gelu, qp precomputed.

#define DOBS 198
#define NEG_INF_F (-3.402823466e38f)

typedef __bf16 v8bf __attribute__((ext_vector_type(8)));
typedef __bf16 v4bf __attribute__((ext_vector_type(4)));
typedef float  v4f  __attribute__((ext_vector_type(4)));

struct P {
  const float *obs,*tok_w,*tok_b,*ln1_s,*ln1_b,
    *a1_qw,*a1_qb,*a1_kw,*a1_kb,*a1_vw,*a1_vb,*a1_ow,*a1_ob,
    *ln2_s,*ln2_b,*m1_w,*m1_b,*m2_w,*m2_b,*m3_w,*m3_b,
    *e1_w,*e1_b,*e2_w,*e2_b,*e3_w,*e3_b,
    *l1_w,*l1_b,*l2_w,*l2_b,*l3_w,*l3_b,
    *seed,*p_qw,*p_qb,*p_kw,*p_kb,*p_vw,*p_vb,*p_ow,*p_ob,
    *pr_w,*pr_b,*h1_w,*h1_b,*h2_w,*h2_b,*h3_w,*h3_b;
  float* out;
};
static_assert(sizeof(P) == 51*sizeof(void*), "P layout");

// ws bf16 weight image, W_t[n][k] per matrix (element offsets)
#define W_A1Q 0
#define W_A1K 4096
#define W_A1V 8192
#define W_A1O 12288
#define W_M1  16384
#define W_M2  24576
#define W_M3  40960
#define W_E1  49152
#define W_E2  53248
#define W_E3  69632
#define W_L1  77824
#define W_L2  94208
#define W_PK  110592
#define W_PV  114688
#define W_PO  118784
#define W_H1  122880
#define W_H2  143360
#define W_H3  159744
#define W_END 176128
#define W_QP  176128   // + 64 f32 (pooling query, precomputed)

__global__ __launch_bounds__(256)
void prep_w(P a, __bf16* ws)
{
  if (blockIdx.x == 172){
    int t = threadIdx.x;
    if (t < 64){
      float acc = a.p_qb[t];
      for (int k=0;k<64;k++) acc += a.seed[k]*a.p_qw[k*64+t];
      ((float*)(ws + W_QP))[t] = acc;
    }
    return;
  }
  const float* srcs[18] = {a.a1_qw,a.a1_kw,a.a1_vw,a.a1_ow,a.m1_w,a.m2_w,a.m3_w,
                           a.e1_w,a.e2_w,a.e3_w,a.l1_w,a.l2_w,a.p_kw,a.p_vw,a.p_ow,
                           a.h1_w,a.h2_w,a.h3_w};
  const int Ks[18]   = {64,64,64,64,64,128,128,32,128,128,128,128,64,64,64,160,128,128};
  const int Ns[18]   = {64,64,64,64,128,128,64,128,128,64,128,128,64,64,64,128,128,128};
  const int offs[18] = {W_A1Q,W_A1K,W_A1V,W_A1O,W_M1,W_M2,W_M3,W_E1,W_E2,W_E3,
                        W_L1,W_L2,W_PK,W_PV,W_PO,W_H1,W_H2,W_H3};
  __shared__ float tile[32][33];
  int b = blockIdx.x, m = 0, acc = 0;
  for (; m < 18; m++){
    int t = (Ks[m]/32)*(Ns[m]/32);
    if (b < acc + t) break;
    acc += t;
  }
  int lt = b - acc, K = Ks[m], N = Ns[m];
  int ntile = N/32, kt = lt/ntile, nt = lt%ntile;
  int tx = threadIdx.x & 31, ty = threadIdx.x >> 5;
  const float* S = srcs[m];
  #pragma unroll
  for (int rr=0; rr<32; rr+=8)
    tile[ty+rr][tx] = S[(size_t)(kt*32+ty+rr)*N + nt*32+tx];
  __syncthreads();
  __bf16* D = ws + offs[m];
  #pragma unroll
  for (int rr=0; rr<32; rr+=8)
    D[(size_t)(nt*32+ty+rr)*K + kt*32+tx] = (__bf16)tile[tx][ty+rr];
}

// gelu(x) = x * sigmoid(2t),  t = 0.79788456(x + 0.044715 x^3)  (exact tanh form)
__device__ __forceinline__ float gelu_f(float x){
  float t = x * fmaf(0.0356774081f, x*x, 0.7978845608f);
  float u = __builtin_amdgcn_exp2f(-2.885390082f * t);
  return x * __builtin_amdgcn_rcpf(1.0f + u);
}

__device__ __forceinline__ void load16f(const __bf16* p, float* f){
  v8bf a = *(const v8bf*)p, b = *(const v8bf*)(p+8);
  #pragma unroll
  for (int i=0;i<8;i++){ f[i]=(float)a[i]; f[8+i]=(float)b[i]; }
}

// N-split block GEMM (round-0 structure): D[40+pad x N] = act @ W + bias.
// Wave wv owns N-tiles wt = wv*NTPW..+NTPW-1; weight frags loaded once per
// N-tile (from L2-hot ws), reused across MT M-tiles. la(mt,kt,ar,quad) ->
// v8bf act fragment from LDS. epi(wbase, mt, ar, c).
template<int KT,int MT,int NTPW,typename LA,typename E>
__device__ __forceinline__ void gemmNS(LA la, const __bf16* __restrict__ Wt,
    const float* __restrict__ bias, int wv, int lane, E epi)
{
  const int ar = lane&15, quad = lane>>4;
  #pragma unroll
  for (int ln=0; ln<NTPW; ln++){
    const int wt = wv*NTPW + ln;
    const __bf16* wp = Wt + (size_t)(wt*16+ar)*(KT*32) + quad*8;
    v8bf wf[KT];
    #pragma unroll
    for (int kt=0;kt<KT;kt++) wf[kt] = *(const v8bf*)(wp + kt*32);
    float4 b4 = *(const float4*)(bias + wt*16 + quad*4);
    #pragma unroll
    for (int mt=0; mt<MT; mt++){
      v4f c; c[0]=b4.x; c[1]=b4.y; c[2]=b4.z; c[3]=b4.w;
      #pragma unroll
      for (int kt=0;kt<KT;kt++)
        c = __builtin_amdgcn_mfma_f32_16x16x32_bf16(wf[kt], la(mt,kt,ar,quad), c, 0,0,0);
      epi(wt*16 + quad*4, mt, ar, c);
    }
  }
}

// LDS map (bytes), total 40736 <= 40960 (4 blocks/CU):
//  Ab   @0      bf16[48][136] 13056  (early: Df f32[8][32])
//  Bb   @13056  bf16[48][136] 13056  (early: TOKIN f32[40][12])
//  Tk   @26112  bf16[48][72]   6912  (early: OBSf f32[8][120]; late: Po bf16[8][64])
//  Pe   @33024  bf16[16][64]   2048
//  Eg   @35072  bf16[16][32]   1024
//  Ru   @36096  bf16[8][30]     480
//  mfb  @36576  bf16[64]        128
//  msfb @36704  bf16[64]        128
//  many @36832  f32[16]          64
//  lga  @36896  f32[48]         192
//  ECX  @37088  bf16[16][64]   2048  (late: Cc bf16[16][64])
//  ATTb @39136  bf16[8][100]   1600  (late: pattn f32[8][20])
__global__ __launch_bounds__(256,4)
void swarm_mfma(P a, const __bf16* __restrict__ ws, int ntok)
{
  __shared__ char smem[40736] __attribute__((aligned(16)));
  __bf16* Ab   = (__bf16*)(smem);
  __bf16* Bb   = (__bf16*)(smem+13056);
  float*  TOKIN= (float*) (smem+13056);
  __bf16* Tk   = (__bf16*)(smem+26112);
  float*  OBSf = (float*) (smem+26112);
  __bf16* Po   = (__bf16*)(smem+26112);
  __bf16* Pe   = (__bf16*)(smem+33024);
  __bf16* Eg   = (__bf16*)(smem+35072);
  __bf16* Ru   = (__bf16*)(smem+36096);
  __bf16* mfb  = (__bf16*)(smem+36576);
  __bf16* msfb = (__bf16*)(smem+36704);
  float*  many = (float*) (smem+36832);
  float*  lga  = (float*) (smem+36896);
  __bf16* ECX  = (__bf16*)(smem+37088);
  __bf16* Cc   = (__bf16*)(smem+37088);
  __bf16* ATTb = (__bf16*)(smem+39136);
  float*  pattn= (float*) (smem+39136);

  const int lane = threadIdx.x & 63;
  const int wv   = threadIdx.x >> 6;
  const int ar   = lane & 15, quad = lane >> 4;
  const long blkT0 = (long)blockIdx.x*8;

  // ================= setup (wave-local tokens 2wv..2wv+1) =================
  for (int it=lane; it<234; it+=64){           // 2*117
    int tg=it/117, c=it-tg*117;
    long gt = blkT0 + 2*wv + tg; if (gt>ntok-1) gt=ntok-1;
    OBSf[(2*wv+tg)*120+c] = a.obs[gt*DOBS+c];
  }
  float* Df = (float*)Ab;
  for (int it=lane; it<50; it+=64){            // 2*25
    int tg=it/25, p=it-tg*25, i=p/5, j=p-i*5;
    const float* ob = OBSf + (2*wv+tg)*120 + 32;
    float d2=0.f;
    #pragma unroll
    for (int d=0;d<3;d++){
      float ri=ob[15*i+d]; ri = isfinite(ri)?ri:0.f;
      float rj=ob[15*j+d]; rj = isfinite(rj)?rj:0.f;
      float df=ri-rj; d2 += df*df;
    }
    Df[(2*wv+tg)*32+p]=sqrtf(d2);
  }
  if (lane<10){
    int T=2*wv+lane/5, s=lane%5;
    const float* b = OBSf + T*120 + 32 + 15*s;
    mfb[10*wv+lane] = (__bf16)((fabsf(b[0])>1e-6f||fabsf(b[1])>1e-6f||fabsf(b[2])>1e-6f)?1.f:0.f);
  }
  if (wv==0 && lane>=40){ mfb[lane]=(__bf16)0.f; msfb[lane]=(__bf16)0.f; }
  if (wv==0 && lane>=8 && lane<16) many[lane]=0.f;
  if (lane<2){
    int T=2*wv+lane;
    float any = (float)mfb[T*5]+(float)mfb[T*5+1]+(float)mfb[T*5+2]+(float)mfb[T*5+3]+(float)mfb[T*5+4];
    float anyf = (any>0.f)?1.f:0.f; many[T]=anyf;
    #pragma unroll
    for (int i=0;i<5;i++) msfb[T*5+i] = (anyf>0.f)? mfb[T*5+i] : (__bf16)((i==0)?1.f:0.f);
  }
  if (lane<10){
    int T=2*wv+lane/5, i=lane%5, R=10*wv+lane;
    float dmin=1e9f,dsum=0.f,cnt=0.f;
    #pragma unroll
    for (int j=0;j<5;j++){
      if (j!=i && (float)mfb[T*5+i]>0.5f && (float)mfb[T*5+j]>0.5f){
        float dd=Df[T*32+i*5+j];
        dmin=fminf(dmin,dd); dsum+=dd; cnt+=1.f;
      }
    }
    TOKIN[R*12+10]=dmin;
    TOKIN[R*12+11]=(cnt>0.f)? dsum/(cnt+1e-9f) : 0.f;
  }
  for (int it=lane; it<100; it+=64){           // 2*50
    int tg=it/50, q=it-tg*50, s=q/10, c=q-s*10;
    int T=2*wv+tg;
    const float* b = OBSf + T*120 + 32 + 15*s;
    float v;
    if (c<4)        v=b[11+c];
    else if (c==4)  v=b[9];
    else if (c==5)  v=b[10];
    else if (c<9)   v=b[6+(c-6)];
    else { float a0=b[6],a1=b[7],a2=b[8]; v=sqrtf(a0*a0+a1*a1+a2*a2); }
    TOKIN[(T*5+s)*12+c]=v;
  }
  for (int it=lane; it<64; it+=64){            // 2*32 (Eg stride 32 now)
    int tg=it>>5, c=it&31;
    Eg[(2*wv+tg)*32+c] = (__bf16)OBSf[(2*wv+tg)*120+c];
  }
  for (int it=lane; it<60; it+=64){            // 2*30
    int tg=it/30, c=it-tg*30;
    Ru[(2*wv+tg)*30+c] = (__bf16)OBSf[(2*wv+tg)*120+32+15*(c/6)+(c%6)];
  }
  for (int it=lane; it<128; it+=64){           // 2*64
    int tg=it>>6, c=it&63;
    float acc = a.pr_b[c];
    #pragma unroll
    for (int k=0;k<10;k++) acc += OBSf[(2*wv+tg)*120+107+k]*a.pr_w[k*64+c];
    Pe[(2*wv+tg)*64+c] = (__bf16)gelu_f(acc);
  }
  __syncthreads();   // S0

  // ---- tok embed (fp32 K=12) -> Tk rows 10wv..10wv+9; then ln1 -> Ab ----
  {
    float w0[12];
    #pragma unroll
    for (int k=0;k<12;k++) w0[k] = a.tok_w[k*64+lane];
    float tb = a.tok_b[lane];
    for (int r=0;r<10;r++){
      int R = 10*wv + r;
      const float4* tin = (const float4*)(TOKIN + R*12);
      float4 x0 = tin[0], x1 = tin[1], x2 = tin[2];
      float acc = tb;
      acc=fmaf(x0.x,w0[0],acc); acc=fmaf(x0.y,w0[1],acc);
      acc=fmaf(x0.z,w0[2],acc); acc=fmaf(x0.w,w0[3],acc);
      acc=fmaf(x1.x,w0[4],acc); acc=fmaf(x1.y,w0[5],acc);
      acc=fmaf(x1.z,w0[6],acc); acc=fmaf(x1.w,w0[7],acc);
      acc=fmaf(x2.x,w0[8],acc); acc=fmaf(x2.y,w0[9],acc);
      acc=fmaf(x2.z,w0[10],acc); acc=fmaf(x2.w,w0[11],acc);
      Tk[R*72+lane] = (__bf16)(gelu_f(acc)*(float)mfb[R]);
    }
  }
  if (ar<10){   // ln1 (shuffles stay within same-ar groups)
    int R = 10*wv + ar;
    float x[16]; load16f(Tk + R*72 + quad*16, x);
    float s=0.f;
    #pragma unroll
    for (int i=0;i<16;i++) s += x[i];
    s += __shfl_xor(s,16,64); s += __shfl_xor(s,32,64);
    float m = s*(1.f/64.f), q=0.f;
    #pragma unroll
    for (int i=0;i<16;i++){ float d=x[i]-m; q=fmaf(d,d,q); }
    q += __shfl_xor(q,16,64); q += __shfl_xor(q,32,64);
    float rs = __builtin_amdgcn_rsqf(q*(1.f/64.f)+1e-6f);
    v8bf o0,o1;
    #pragma unroll
    for (int i=0;i<8;i++){
      o0[i]=(__bf16)((x[i]  -m)*rs*a.ln1_s[quad*16+i]  +a.ln1_b[quad*16+i]);
      o1[i]=(__bf16)((x[8+i]-m)*rs*a.ln1_s[quad*16+8+i]+a.ln1_b[quad*16+8+i]);
    }
    *(v8bf*)(Ab+R*136+quad*16)=o0; *(v8bf*)(Ab+R*136+quad*16+8)=o1;
  }
  __syncthreads();   // S1

  auto actAb = [&](int mt,int kt,int r,int q){ return *(const v8bf*)(Ab + (size_t)(mt*16+r)*136 + q*8 + kt*32); };
  auto actBb = [&](int mt,int kt,int r,int q){ return *(const v8bf*)(Bb + (size_t)(mt*16+r)*136 + q*8 + kt*32); };
  auto actTk = [&](int mt,int kt,int r,int q){ return *(const v8bf*)(Tk + (size_t)(mt*16+r)*72  + q*8 + kt*32); };

  // ---- QKV: K -> Bb[:,64:], V -> Ab[:,64:], Q -> Bb[:,0:64] ----
  gemmNS<2,3,1>(actAb, ws+W_A1K, a.a1_kb, wv, lane,
    [&](int wb,int mt,int r,v4f c){ v4bf o;
      #pragma unroll
      for (int k=0;k<4;k++) o[k]=(__bf16)c[k];
      *(v4bf*)&Bb[(mt*16+r)*136+64+wb]=o; });
  gemmNS<2,3,1>(actAb, ws+W_A1V, a.a1_vb, wv, lane,
    [&](int wb,int mt,int r,v4f c){ v4bf o;
      #pragma unroll
      for (int k=0;k<4;k++) o[k]=(__bf16)c[k];
      *(v4bf*)&Ab[(mt*16+r)*136+64+wb]=o; });
  gemmNS<2,3,1>(actAb, ws+W_A1Q, a.a1_qb, wv, lane,
    [&](int wb,int mt,int r,v4f c){ v4bf o;
      #pragma unroll
      for (int k=0;k<4;k++) o[k]=(__bf16)c[k];
      *(v4bf*)&Bb[(mt*16+r)*136+wb]=o; });
  __syncthreads();   // S2

  // ---- attn weights + attn@V (wave-local tokens) ----
  if (lane<40){
    int tg=lane/20, rem=lane-tg*20, h=rem/5, i=rem-h*5;
    int T=2*wv+tg;
    bool mi = (float)msfb[T*5+i]>0.5f;
    float qv[16]; load16f(&Bb[(T*5+i)*136 + h*16], qv);
    float lgv[5], mx=NEG_INF_F;
    #pragma unroll
    for (int j=0;j<5;j++){
      float kk[16]; load16f(&Bb[(T*5+j)*136 + 64 + h*16], kk);
      float d=0.f;
      #pragma unroll
      for (int dd=0;dd<16;dd++) d += qv[dd]*kk[dd];
      bool mj = (float)msfb[T*5+j]>0.5f;
      lgv[j] = (mi&&mj)? d*0.25f : NEG_INF_F;
      mx = fmaxf(mx,lgv[j]);
    }
    float sum=0.f, ex[5];
    #pragma unroll
    for (int j=0;j<5;j++){ ex[j]=__expf(lgv[j]-mx); sum+=ex[j]; }
    float inv=1.0f/sum;
    #pragma unroll
    for (int j=0;j<5;j++) ATTb[T*100+(h*5+i)*5+j]=(__bf16)(ex[j]*inv);
  }
  {
    int h = lane>>4;
    #pragma unroll
    for (int tg=0; tg<2; tg++){
      int T=2*wv+tg;
      float v5[5];
      #pragma unroll
      for (int j=0;j<5;j++) v5[j] = (float)Ab[(T*5+j)*136+64+lane];
      #pragma unroll
      for (int i=0;i<5;i++){
        float o=0.f;
        #pragma unroll
        for (int j=0;j<5;j++) o += (float)ATTb[T*100+(h*5+i)*5+j]*v5[j];
        Ab[(T*5+i)*136+lane]=(__bf16)o;
      }
    }
  }
  __syncthreads();   // S3

  // ---- o-proj + residual -> Tk ----
  gemmNS<2,3,1>(actAb, ws+W_A1O, a.a1_ob, wv, lane,
    [&](int wb,int mt,int r,v4f c){
      int R=mt*16+r; float mm=(float)mfb[R];
      v4bf old=*(const v4bf*)&Tk[R*72+wb]; v4bf o;
      #pragma unroll
      for (int k=0;k<4;k++) o[k]=(__bf16)((float)old[k]+c[k]*mm);
      *(v4bf*)&Tk[R*72+wb]=o; });
  __syncthreads();   // S4

  // ---- ln2 -> Ab[:,0:64] ----
  if (ar<10){
    int R = 10*wv + ar;
    float x[16]; load16f(Tk + R*72 + quad*16, x);
    float s=0.f;
    #pragma unroll
    for (int i=0;i<16;i++) s += x[i];
    s += __shfl_xor(s,16,64); s += __shfl_xor(s,32,64);
    float m = s*(1.f/64.f), q=0.f;
    #pragma unroll
    for (int i=0;i<16;i++){ float d=x[i]-m; q=fmaf(d,d,q); }
    q += __shfl_xor(q,16,64); q += __shfl_xor(q,32,64);
    float rs = __builtin_amdgcn_rsqf(q*(1.f/64.f)+1e-6f);
    v8bf o0,o1;
    #pragma unroll
    for (int i=0;i<8;i++){
      o0[i]=(__bf16)((x[i]  -m)*rs*a.ln2_s[quad*16+i]  +a.ln2_b[quad*16+i]);
      o1[i]=(__bf16)((x[8+i]-m)*rs*a.ln2_s[quad*16+8+i]+a.ln2_b[quad*16+8+i]);
    }
    *(v8bf*)(Ab+R*136+quad*16)=o0; *(v8bf*)(Ab+R*136+quad*16+8)=o1;
  }
  __syncthreads();   // S5

  // ---- m1 -> Bb[:,0:128] ----
  gemmNS<2,3,2>(actAb, ws+W_M1, a.m1_b, wv, lane,
    [&](int wb,int mt,int r,v4f c){ v4bf o;
      #pragma unroll
      for (int k=0;k<4;k++) o[k]=(__bf16)gelu_f(c[k]);
      *(v4bf*)&Bb[(mt*16+r)*136+wb]=o; });
  __syncthreads();   // S6
  // ---- m2 -> Ab[:,0:128] ----
  gemmNS<4,3,2>(actBb, ws+W_M2, a.m2_b, wv, lane,
    [&](int wb,int mt,int r,v4f c){ v4bf o;
      #pragma unroll
      for (int k=0;k<4;k++) o[k]=(__bf16)gelu_f(c[k]);
      *(v4bf*)&Ab[(mt*16+r)*136+wb]=o; });
  __syncthreads();   // S7
  // ---- m3 -> Tk (resid*mask) ; e1 (token-level) -> Bb rows 0..15 ----
  gemmNS<4,3,1>(actAb, ws+W_M3, a.m3_b, wv, lane,
    [&](int wb,int mt,int r,v4f c){
      int R=mt*16+r; float mm=(float)mfb[R];
      v4bf old=*(const v4bf*)&Tk[R*72+wb]; v4bf o;
      #pragma unroll
      for (int k=0;k<4;k++) o[k]=(__bf16)(((float)old[k]+c[k]*mm)*mm);
      *(v4bf*)&Tk[R*72+wb]=o; });
  gemmNS<1,1,2>([&](int,int,int r,int q){ return *(const v8bf*)(Eg + (size_t)r*32 + q*8); },
    ws+W_E1, a.e1_b, wv, lane,
    [&](int wb,int mt,int r,v4f c){ v4bf o;
      #pragma unroll
      for (int k=0;k<4;k++) o[k]=(__bf16)gelu_f(c[k]);
      *(v4bf*)&Bb[r*136+wb]=o; });
  __syncthreads();   // S8
  // ---- e2 -> Ab rows 0..15 ----
  gemmNS<4,1,2>(actBb, ws+W_E2, a.e2_b, wv, lane,
    [&](int wb,int mt,int r,v4f c){ v4bf o;
      #pragma unroll
      for (int k=0;k<4;k++) o[k]=(__bf16)gelu_f(c[k]);
      *(v4bf*)&Ab[r*136+wb]=o; });
  __syncthreads();   // S9
  // ---- e3 -> ECX rows 0..15 ----
  gemmNS<4,1,1>(actAb, ws+W_E3, a.e3_b, wv, lane,
    [&](int wb,int mt,int r,v4f c){ v4bf o;
      #pragma unroll
      for (int k=0;k<4;k++) o[k]=(__bf16)c[k];
      *(v4bf*)&ECX[r*64+wb]=o; });
  __syncthreads();   // S10
  // ---- l1 (act = [Tk | ECX(token)]) -> Bb[:,0:128] ----
  gemmNS<4,3,2>([&](int mt,int kt,int r,int q){
      int R=mt*16+r;
      return (kt<2) ? *(const v8bf*)(Tk + (size_t)R*72 + q*8 + kt*32)
                    : *(const v8bf*)(ECX + (size_t)((R*205)>>10)*64 + q*8 + (kt-2)*32); },
    ws+W_L1, a.l1_b, wv, lane,
    [&](int wb,int mt,int r,v4f c){ v4bf o;
      #pragma unroll
      for (int k=0;k<4;k++) o[k]=(__bf16)gelu_f(c[k]);
      *(v4bf*)&Bb[(mt*16+r)*136+wb]=o; });
  __syncthreads();   // S11
  // ---- l2 -> Ab[:,0:128] ----
  gemmNS<4,3,2>(actBb, ws+W_L2, a.l2_b, wv, lane,
    [&](int wb,int mt,int r,v4f c){ v4bf o;
      #pragma unroll
      for (int k=0;k<4;k++) o[k]=(__bf16)gelu_f(c[k]);
      *(v4bf*)&Ab[(mt*16+r)*136+wb]=o; });
  __syncthreads();   // S12

  // ---- l3 (own rows) + alpha + v_r/v_u ; kp/vp -> Bb ----
  if (ar<10){
    int R = 10*wv + ar;
    float x[16], y[16];
    load16f(&Ab[R*136 + quad*32], x);
    load16f(&Ab[R*136 + quad*32 + 16], y);
    const float* w = a.l3_w + quad*32;
    float p = 0.f;
    #pragma unroll
    for (int i=0;i<16;i++) p = fmaf(x[i], w[i], p);
    #pragma unroll
    for (int i=0;i<16;i++) p = fmaf(y[i], w[16+i], p);
    p += __shfl_xor(p,16,64); p += __shfl_xor(p,32,64);
    if (quad==0) lga[R] = p + a.l3_b[0];
  }
  gemmNS<2,3,1>(actTk, ws+W_PK, a.p_kb, wv, lane,
    [&](int wb,int mt,int r,v4f c){ v4bf o;
      #pragma unroll
      for (int k=0;k<4;k++) o[k]=(__bf16)c[k];
      *(v4bf*)&Bb[(mt*16+r)*136+wb]=o; });
  gemmNS<2,3,1>(actTk, ws+W_PV, a.p_vb, wv, lane,
    [&](int wb,int mt,int r,v4f c){ v4bf o;
      #pragma unroll
      for (int k=0;k<4;k++) o[k]=(__bf16)c[k];
      *(v4bf*)&Bb[(mt*16+r)*136+64+wb]=o; });
  if (lane<2){
    int T=2*wv+lane;
    float ml[5], mx=-1e9f;
    #pragma unroll
    for (int i=0;i<5;i++){ ml[i]=((float)mfb[T*5+i]>0.5f)? lga[T*5+i] : -1e9f; mx=fmaxf(mx,ml[i]); }
    float den=0.f, e[5];
    #pragma unroll
    for (int i=0;i<5;i++){ e[i]=__expf(ml[i]-mx)*(float)mfb[T*5+i]; den+=e[i]; }
    float inv=1.0f/(den+1e-9f);
    #pragma unroll
    for (int i=0;i<5;i++) lga[T*5+i]=e[i]*inv;
  }
  if (lane<12){
    int tg=lane/6, c=lane-tg*6;
    int T=2*wv+tg;
    float v=0.f;
    #pragma unroll
    for (int i=0;i<5;i++) v += lga[T*5+i]*(float)Ru[T*30+i*6+c];
    long tk = blkT0 + T;
    if (tk<ntok) a.out[tk*134+128+c]=v;
  }
  __syncthreads();   // S13

  // ---- pooling attn + pooled-o (wave-local tokens) ----
  if (lane<8){
    const float* qg = (const float*)(ws + W_QP);
    int tg=lane>>2, h=lane&3;
    int T=2*wv+tg;
    float qv[16];
    #pragma unroll
    for (int dd=0;dd<16;dd++) qv[dd]=qg[h*16+dd];
    float lgv[5], mx=NEG_INF_F;
    #pragma unroll
    for (int j=0;j<5;j++){
      float kk[16]; load16f(&Bb[(T*5+j)*136 + h*16], kk);
      float d=0.f;
      #pragma unroll
      for (int dd=0;dd<16;dd++) d += qv[dd]*kk[dd];
      lgv[j] = ((float)msfb[T*5+j]>0.5f)? d*0.25f : NEG_INF_F;
      mx = fmaxf(mx,lgv[j]);
    }
    float sum=0.f, ex[5];
    #pragma unroll
    for (int j=0;j<5;j++){ ex[j]=__expf(lgv[j]-mx); sum+=ex[j]; }
    float inv=1.0f/sum;
    #pragma unroll
    for (int j=0;j<5;j++) pattn[T*20+h*5+j]=ex[j]*inv;
  }
  for (int it=lane; it<128; it+=64){
    int tg=it>>6, c=it&63, h=c>>4;
    int T=2*wv+tg;
    float o=0.f;
    #pragma unroll
    for (int j=0;j<5;j++)
      o += pattn[T*20+h*5+j]*(float)Bb[(T*5+j)*136+64+c];
    Po[T*64+c]=(__bf16)o;
  }
  __syncthreads();   // S14

  // ---- p_ow -> Cc (x many) ----
  gemmNS<2,1,1>([&](int,int kt,int r,int q){ return *(const v8bf*)(Po + (size_t)r*64 + q*8 + kt*32); },
    ws+W_PO, a.p_ob, wv, lane,
    [&](int wb,int mt,int r,v4f c){
      float mm = many[r];
      v4bf o;
      #pragma unroll
      for (int k=0;k<4;k++) o[k]=(__bf16)(c[k]*mm);
      *(v4bf*)&Cc[r*64+wb]=o; });
  __syncthreads();   // S15

  // ---- h1 (act = [Eg | Cc | Pe], K=160) -> Bb rows 0..15 ----
  gemmNS<5,1,2>([&](int,int kt,int r,int q){
      if (kt==0) return *(const v8bf*)(Eg + (size_t)r*32 + q*8);
      if (kt<3)  return *(const v8bf*)(Cc + (size_t)r*64 + q*8 + (kt-1)*32);
      return *(const v8bf*)(Pe + (size_t)r*64 + q*8 + (kt-3)*32); },
    ws+W_H1, a.h1_b, wv, lane,
    [&](int wb,int mt,int r,v4f c){ v4bf o;
      #pragma unroll
      for (int k=0;k<4;k++) o[k]=(__bf16)gelu_f(c[k]);
      *(v4bf*)&Bb[r*136+wb]=o; });
  __syncthreads();   // S16
  // ---- h2 -> Ab rows 0..15 ----
  gemmNS<4,1,2>(actBb, ws+W_H2, a.h2_b, wv, lane,
    [&](int wb,int mt,int r,v4f c){ v4bf o;
      #pragma unroll
      for (int k=0;k<4;k++) o[k]=(__bf16)gelu_f(c[k]);
      *(v4bf*)&Ab[r*136+wb]=o; });
  __syncthreads();   // S17
  // ---- h3 -> out ----
  gemmNS<4,1,2>(actAb, ws+W_H3, a.h3_b, wv, lane,
    [&](int wb,int mt,int r,v4f c){
      long tk = blkT0 + r;
      if (r<8 && tk<ntok){
        float2* o2 = (float2*)&a.out[tk*134 + wb];
        o2[0] = make_float2(c[0], c[1]);
        o2[1] = make_float2(c[2], c[3]);
      } });
}

extern "C" void kernel_launch(void* const* d_in, const int* in_sizes, int n_in,
                              void* d_out, int out_size, void* d_ws, size_t ws_size,
                              hipStream_t stream)
{
  P a;
  const float** pp = reinterpret_cast<const float**>(&a);
  for (int i=0;i<50;i++) pp[i] = reinterpret_cast<const float*>(d_in[i]);
  a.out = reinterpret_cast<float*>(d_out);
  int ntok = in_sizes[0] / DOBS;   // 65536

  __bf16* ws = reinterpret_cast<__bf16*>(d_ws);
  hipLaunchKernelGGL(prep_w, dim3(173), dim3(256), 0, stream, a, ws);
  hipLaunchKernelGGL(swarm_mfma, dim3((ntok+7)/8), dim3(256), 0, stream, a, ws, ntok);
}

// Round 8
// 497.854 us; speedup vs baseline: 1.2087x; 1.1420x over previous
//
#include <hip/hip_runtime.h>
#include <math.h>

// SwarmSetEquivariantTorso — bf16 MFMA, N-split block GEMMs, 12 tok/block.
// HISTORY: R0 baseline 375us (MfmaUtil 8.8, VALUBusy 47, Occ 32.5).
// R5 act-reuse restructure: 463us (global weight batching stalled waves).
// R7 8-tok/4-blocks-CU: 437us (Occ 44 as predicted, but +23% VALU work from
// per-block fixed costs; +35% waves gave only +5.7% issue throughput —
// idle is NOT occupancy-fillable; it's the serial 18-barrier layer chain).
// THIS VERSION = R0 body + ONE isolated change: cross-barrier weight
// prefetch. wload() issues next layer's weight-frag loads BEFORE the
// barrier; BAR() = s_waitcnt lgkmcnt(0) + raw s_barrier (no vmcnt drain,
// m201-proven pattern) so the loads stay in flight across it. Removes the
// ~200-400cyc per-layer post-barrier L2 entry stall. Math bit-identical.

#define DOBS 198
#define NEG_INF_F (-3.402823466e38f)

// Non-draining barrier: LDS visibility via lgkmcnt(0); global (weight)
// loads stay in flight. No cross-wave global communication in-kernel.
#define BAR() do { asm volatile("s_waitcnt lgkmcnt(0)" ::: "memory"); \
                   __builtin_amdgcn_s_barrier(); } while(0)

typedef __bf16 v8bf __attribute__((ext_vector_type(8)));
typedef __bf16 v4bf __attribute__((ext_vector_type(4)));
typedef float  v4f  __attribute__((ext_vector_type(4)));

struct P {
  const float *obs,*tok_w,*tok_b,*ln1_s,*ln1_b,
    *a1_qw,*a1_qb,*a1_kw,*a1_kb,*a1_vw,*a1_vb,*a1_ow,*a1_ob,
    *ln2_s,*ln2_b,*m1_w,*m1_b,*m2_w,*m2_b,*m3_w,*m3_b,
    *e1_w,*e1_b,*e2_w,*e2_b,*e3_w,*e3_b,
    *l1_w,*l1_b,*l2_w,*l2_b,*l3_w,*l3_b,
    *seed,*p_qw,*p_qb,*p_kw,*p_kb,*p_vw,*p_vb,*p_ow,*p_ob,
    *pr_w,*pr_b,*h1_w,*h1_b,*h2_w,*h2_b,*h3_w,*h3_b;
  float* out;
};
static_assert(sizeof(P) == 51*sizeof(void*), "P layout");

// ws bf16 weight image, W_t[n][k] per matrix (element offsets)
#define W_A1Q 0
#define W_A1K 4096
#define W_A1V 8192
#define W_A1O 12288
#define W_M1  16384
#define W_M2  24576
#define W_M3  40960
#define W_E1  49152
#define W_E2  53248
#define W_E3  69632
#define W_L1  77824
#define W_L2  94208
#define W_PK  110592
#define W_PV  114688
#define W_PO  118784
#define W_H1  122880
#define W_H2  143360
#define W_H3  159744
#define W_END 176128
#define W_QP  176128   // + 64 f32 (pooling query, precomputed)

__global__ __launch_bounds__(256)
void prep_w(P a, __bf16* ws)
{
  if (blockIdx.x == 172){
    int t = threadIdx.x;
    if (t < 64){
      float acc = a.p_qb[t];
      for (int k=0;k<64;k++) acc += a.seed[k]*a.p_qw[k*64+t];
      ((float*)(ws + W_QP))[t] = acc;
    }
    return;
  }
  const float* srcs[18] = {a.a1_qw,a.a1_kw,a.a1_vw,a.a1_ow,a.m1_w,a.m2_w,a.m3_w,
                           a.e1_w,a.e2_w,a.e3_w,a.l1_w,a.l2_w,a.p_kw,a.p_vw,a.p_ow,
                           a.h1_w,a.h2_w,a.h3_w};
  const int Ks[18]   = {64,64,64,64,64,128,128,32,128,128,128,128,64,64,64,160,128,128};
  const int Ns[18]   = {64,64,64,64,128,128,64,128,128,64,128,128,64,64,64,128,128,128};
  const int offs[18] = {W_A1Q,W_A1K,W_A1V,W_A1O,W_M1,W_M2,W_M3,W_E1,W_E2,W_E3,
                        W_L1,W_L2,W_PK,W_PV,W_PO,W_H1,W_H2,W_H3};
  __shared__ float tile[32][33];
  int b = blockIdx.x, m = 0, acc = 0;
  for (; m < 18; m++){
    int t = (Ks[m]/32)*(Ns[m]/32);
    if (b < acc + t) break;
    acc += t;
  }
  int lt = b - acc, K = Ks[m], N = Ns[m];
  int ntile = N/32, kt = lt/ntile, nt = lt%ntile;
  int tx = threadIdx.x & 31, ty = threadIdx.x >> 5;
  const float* S = srcs[m];
  #pragma unroll
  for (int rr=0; rr<32; rr+=8)
    tile[ty+rr][tx] = S[(size_t)(kt*32+ty+rr)*N + nt*32+tx];
  __syncthreads();
  __bf16* D = ws + offs[m];
  #pragma unroll
  for (int rr=0; rr<32; rr+=8)
    D[(size_t)(nt*32+ty+rr)*K + kt*32+tx] = (__bf16)tile[tx][ty+rr];
}

// gelu(x) = x * sigmoid(2t),  t = 0.79788456(x + 0.044715 x^3)  (exact tanh form)
__device__ __forceinline__ float gelu_f(float x){
  float t = x * fmaf(0.0356774081f, x*x, 0.7978845608f);
  float u = __builtin_amdgcn_exp2f(-2.885390082f * t);
  return x * __builtin_amdgcn_rcpf(1.0f + u);
}

__device__ __forceinline__ void load16f(const __bf16* p, float* f){
  v8bf a = *(const v8bf*)p, b = *(const v8bf*)(p+8);
  #pragma unroll
  for (int i=0;i<8;i++){ f[i]=(float)a[i]; f[8+i]=(float)b[i]; }
}

// Weight fragments for one N-split gemm call: issued early (prefetch),
// consumed after the next barrier. All indices compile-time (stays in regs).
template<int KT,int NTPW> struct WF {
  v8bf  w[NTPW][KT];
  float4 b[NTPW];
};

template<int KT,int NTPW>
__device__ __forceinline__ WF<KT,NTPW> wload(const __bf16* __restrict__ Wt,
    const float* __restrict__ bias, int wv, int lane)
{
  WF<KT,NTPW> f;
  const int ar = lane&15, quad = lane>>4;
  #pragma unroll
  for (int ln=0; ln<NTPW; ln++){
    const int wt = wv*NTPW + ln;
    const __bf16* wp = Wt + (size_t)(wt*16+ar)*(KT*32) + quad*8;
    #pragma unroll
    for (int kt=0;kt<KT;kt++) f.w[ln][kt] = *(const v8bf*)(wp + kt*32);
    f.b[ln] = *(const float4*)(bias + wt*16 + quad*4);
  }
  return f;
}

// N-split block GEMM consuming prefetched weights: D[60+pad x N] = act@W+b.
// Wave wv owns N-tiles wv*NTPW..; loops MT M-tiles; act frags from LDS.
template<int KT,int MT,int NTPW,typename LA,typename E>
__device__ __forceinline__ void gemmW(LA la, const WF<KT,NTPW>& f,
    int wv, int lane, E epi)
{
  const int ar = lane&15, quad = lane>>4;
  #pragma unroll
  for (int ln=0; ln<NTPW; ln++){
    const int wt = wv*NTPW + ln;
    #pragma unroll
    for (int mt=0; mt<MT; mt++){
      v4f c; c[0]=f.b[ln].x; c[1]=f.b[ln].y; c[2]=f.b[ln].z; c[3]=f.b[ln].w;
      #pragma unroll
      for (int kt=0;kt<KT;kt++)
        c = __builtin_amdgcn_mfma_f32_16x16x32_bf16(f.w[ln][kt], la(mt,kt,ar,quad), c, 0,0,0);
      epi(wt*16 + quad*4, mt, ar, c);
    }
  }
}

// LDS map (bytes), total 53120 <= 53248 (proven 3 blocks/CU):
//  Ab   @0      bf16[64][136] 17408  (early: Df f32[12][32])
//  Bb   @17408  bf16[64][136] 17408  (early: TOKIN f32[60][12])
//  Tk   @34816  bf16[64][72]   9216  (early: OBSf f32[12][120]; late: Po bf16[12][64])
//  Pe   @44032  bf16[16][64]   2048
//  Eg   @46080  bf16[16][40]   1280
//  Ru   @47360  bf16[12][30]    736
//  mfb  @48096  bf16[64]        128
//  msfb @48224  bf16[64]        128
//  many @48352  f32[16]          64
//  lga  @48416  f32[64]         256
//  ECX  @48672  bf16[16][64]   2048  (late: pattn f32[12][20])
//  ATTb @50720  bf16[12][100]  2400  (late: Cc bf16[16][64])
__global__ __launch_bounds__(256,3)
void swarm_mfma(P a, const __bf16* __restrict__ ws, int ntok)
{
  __shared__ char smem[53120] __attribute__((aligned(16)));
  __bf16* Ab   = (__bf16*)(smem);
  __bf16* Bb   = (__bf16*)(smem+17408);
  float*  TOKIN= (float*) (smem+17408);
  __bf16* Tk   = (__bf16*)(smem+34816);
  float*  OBSf = (float*) (smem+34816);
  __bf16* Po   = (__bf16*)(smem+34816);
  __bf16* Pe   = (__bf16*)(smem+44032);
  __bf16* Eg   = (__bf16*)(smem+46080);
  __bf16* Ru   = (__bf16*)(smem+47360);
  __bf16* mfb  = (__bf16*)(smem+48096);
  __bf16* msfb = (__bf16*)(smem+48224);
  float*  many = (float*) (smem+48352);
  float*  lga  = (float*) (smem+48416);
  __bf16* ECX  = (__bf16*)(smem+48672);
  float*  pattn= (float*) (smem+48672);
  __bf16* ATTb = (__bf16*)(smem+50720);
  __bf16* Cc   = (__bf16*)(smem+50720);

  const int lane = threadIdx.x & 63;
  const int wv   = threadIdx.x >> 6;
  const int ar   = lane & 15, quad = lane >> 4;
  const long blkT0 = (long)blockIdx.x*12;

  // ================= setup (wave-local tokens 3wv..3wv+2) =================
  for (int it=lane; it<3*117; it+=64){
    int tg=it/117, c=it-tg*117;
    long gt = blkT0 + 3*wv + tg; if (gt>ntok-1) gt=ntok-1;
    OBSf[(3*wv+tg)*120+c] = a.obs[gt*DOBS+c];
  }
  float* Df = (float*)Ab;
  for (int it=lane; it<75; it+=64){
    int tg=it/25, p=it-tg*25, i=p/5, j=p-i*5;
    const float* ob = OBSf + (3*wv+tg)*120 + 32;
    float d2=0.f;
    #pragma unroll
    for (int d=0;d<3;d++){
      float ri=ob[15*i+d]; ri = isfinite(ri)?ri:0.f;
      float rj=ob[15*j+d]; rj = isfinite(rj)?rj:0.f;
      float df=ri-rj; d2 += df*df;
    }
    Df[(3*wv+tg)*32+p]=sqrtf(d2);
  }
  if (lane<15){
    int T=3*wv+lane/5, s=lane%5;
    const float* b = OBSf + T*120 + 32 + 15*s;
    mfb[15*wv+lane] = (__bf16)((fabsf(b[0])>1e-6f||fabsf(b[1])>1e-6f||fabsf(b[2])>1e-6f)?1.f:0.f);
  }
  if (wv==0 && lane>=60){ mfb[lane]=(__bf16)0.f; msfb[lane]=(__bf16)0.f; }
  if (wv==0 && lane>=12 && lane<16) many[lane]=0.f;
  if (lane<3){
    int T=3*wv+lane;
    float any = (float)mfb[T*5]+(float)mfb[T*5+1]+(float)mfb[T*5+2]+(float)mfb[T*5+3]+(float)mfb[T*5+4];
    float anyf = (any>0.f)?1.f:0.f; many[T]=anyf;
    #pragma unroll
    for (int i=0;i<5;i++) msfb[T*5+i] = (anyf>0.f)? mfb[T*5+i] : (__bf16)((i==0)?1.f:0.f);
  }
  if (lane<15){
    int T=3*wv+lane/5, i=lane%5, R=15*wv+lane;
    float dmin=1e9f,dsum=0.f,cnt=0.f;
    #pragma unroll
    for (int j=0;j<5;j++){
      if (j!=i && (float)mfb[T*5+i]>0.5f && (float)mfb[T*5+j]>0.5f){
        float dd=Df[T*32+i*5+j];
        dmin=fminf(dmin,dd); dsum+=dd; cnt+=1.f;
      }
    }
    TOKIN[R*12+10]=dmin;
    TOKIN[R*12+11]=(cnt>0.f)? dsum/(cnt+1e-9f) : 0.f;
  }
  for (int it=lane; it<150; it+=64){
    int tg=it/50, q=it-tg*50, s=q/10, c=q-s*10;
    int T=3*wv+tg;
    const float* b = OBSf + T*120 + 32 + 15*s;
    float v;
    if (c<4)        v=b[11+c];
    else if (c==4)  v=b[9];
    else if (c==5)  v=b[10];
    else if (c<9)   v=b[6+(c-6)];
    else { float a0=b[6],a1=b[7],a2=b[8]; v=sqrtf(a0*a0+a1*a1+a2*a2); }
    TOKIN[(T*5+s)*12+c]=v;
  }
  for (int it=lane; it<96; it+=64){
    int tg=it>>5, c=it&31;
    Eg[(3*wv+tg)*40+c] = (__bf16)OBSf[(3*wv+tg)*120+c];
  }
  for (int it=lane; it<90; it+=64){
    int tg=it/30, c=it-tg*30;
    Ru[(3*wv+tg)*30+c] = (__bf16)OBSf[(3*wv+tg)*120+32+15*(c/6)+(c%6)];
  }
  for (int it=lane; it<192; it+=64){
    int tg=it>>6, c=it&63;
    float acc = a.pr_b[c];
    #pragma unroll
    for (int k=0;k<10;k++) acc += OBSf[(3*wv+tg)*120+107+k]*a.pr_w[k*64+c];
    Pe[(3*wv+tg)*64+c] = (__bf16)gelu_f(acc);
  }
  BAR();   // S0: OBSf/Df/TOKIN producers done; Tk writes may begin

  // prefetch first gemm's weights; overlaps tok-embed + ln1
  auto wfK = wload<2,1>(ws+W_A1K, a.a1_kb, wv, lane);

  // ---- P3: tok embed (fp32 K=12) -> Tk rows 15wv..15wv+14; then ln1 -> Ab ----
  {
    float w0[12];
    #pragma unroll
    for (int k=0;k<12;k++) w0[k] = a.tok_w[k*64+lane];
    float tb = a.tok_b[lane];
    for (int r=0;r<15;r++){
      int R = 15*wv + r;
      const float4* tin = (const float4*)(TOKIN + R*12);
      float4 x0 = tin[0], x1 = tin[1], x2 = tin[2];
      float acc = tb;
      acc=fmaf(x0.x,w0[0],acc); acc=fmaf(x0.y,w0[1],acc);
      acc=fmaf(x0.z,w0[2],acc); acc=fmaf(x0.w,w0[3],acc);
      acc=fmaf(x1.x,w0[4],acc); acc=fmaf(x1.y,w0[5],acc);
      acc=fmaf(x1.z,w0[6],acc); acc=fmaf(x1.w,w0[7],acc);
      acc=fmaf(x2.x,w0[8],acc); acc=fmaf(x2.y,w0[9],acc);
      acc=fmaf(x2.z,w0[10],acc); acc=fmaf(x2.w,w0[11],acc);
      Tk[R*72+lane] = (__bf16)(gelu_f(acc)*(float)mfb[R]);
    }
  }
  if (ar<15){   // ln1, own rows (shuffles stay within same-ar groups)
    int R = 15*wv + ar;
    float x[16]; load16f(Tk + R*72 + quad*16, x);
    float s=0.f;
    #pragma unroll
    for (int i=0;i<16;i++) s += x[i];
    s += __shfl_xor(s,16,64); s += __shfl_xor(s,32,64);
    float m = s*(1.f/64.f), q=0.f;
    #pragma unroll
    for (int i=0;i<16;i++){ float d=x[i]-m; q=fmaf(d,d,q); }
    q += __shfl_xor(q,16,64); q += __shfl_xor(q,32,64);
    float rs = __builtin_amdgcn_rsqf(q*(1.f/64.f)+1e-6f);
    v8bf o0,o1;
    #pragma unroll
    for (int i=0;i<8;i++){
      o0[i]=(__bf16)((x[i]  -m)*rs*a.ln1_s[quad*16+i]  +a.ln1_b[quad*16+i]);
      o1[i]=(__bf16)((x[8+i]-m)*rs*a.ln1_s[quad*16+8+i]+a.ln1_b[quad*16+8+i]);
    }
    *(v8bf*)(Ab+R*136+quad*16)=o0; *(v8bf*)(Ab+R*136+quad*16+8)=o1;
  }
  BAR();   // S1

  auto actAb = [&](int mt,int kt,int r,int q){ return *(const v8bf*)(Ab + (size_t)(mt*16+r)*136 + q*8 + kt*32); };
  auto actBb = [&](int mt,int kt,int r,int q){ return *(const v8bf*)(Bb + (size_t)(mt*16+r)*136 + q*8 + kt*32); };
  auto actTk = [&](int mt,int kt,int r,int q){ return *(const v8bf*)(Tk + (size_t)(mt*16+r)*72  + q*8 + kt*32); };

  // ---- QKV: K -> Bb[:,64:], V -> Ab[:,64:], Q -> Bb[:,0:64] ----
  // V/Q weight loads issue up front; latency hides under K's MFMAs.
  auto wfV = wload<2,1>(ws+W_A1V, a.a1_vb, wv, lane);
  auto wfQ = wload<2,1>(ws+W_A1Q, a.a1_qb, wv, lane);
  gemmW<2,4,1>(actAb, wfK, wv, lane,
    [&](int wb,int mt,int r,v4f c){ v4bf o;
      #pragma unroll
      for (int k=0;k<4;k++) o[k]=(__bf16)c[k];
      *(v4bf*)&Bb[(mt*16+r)*136+64+wb]=o; });
  gemmW<2,4,1>(actAb, wfV, wv, lane,
    [&](int wb,int mt,int r,v4f c){ v4bf o;
      #pragma unroll
      for (int k=0;k<4;k++) o[k]=(__bf16)c[k];
      *(v4bf*)&Ab[(mt*16+r)*136+64+wb]=o; });
  gemmW<2,4,1>(actAb, wfQ, wv, lane,
    [&](int wb,int mt,int r,v4f c){ v4bf o;
      #pragma unroll
      for (int k=0;k<4;k++) o[k]=(__bf16)c[k];
      *(v4bf*)&Bb[(mt*16+r)*136+wb]=o; });
  auto wfO = wload<2,1>(ws+W_A1O, a.a1_ob, wv, lane);   // survives S2+S3
  BAR();   // S2

  // ---- attn weights + attn@V (wave-local tokens) ----
  if (lane<60){
    int tg=lane/20, rem=lane-tg*20, h=rem/5, i=rem-h*5;
    int T=3*wv+tg;
    bool mi = (float)msfb[T*5+i]>0.5f;
    float qv[16]; load16f(&Bb[(T*5+i)*136 + h*16], qv);
    float lgv[5], mx=NEG_INF_F;
    #pragma unroll
    for (int j=0;j<5;j++){
      float kk[16]; load16f(&Bb[(T*5+j)*136 + 64 + h*16], kk);
      float d=0.f;
      #pragma unroll
      for (int dd=0;dd<16;dd++) d += qv[dd]*kk[dd];
      bool mj = (float)msfb[T*5+j]>0.5f;
      lgv[j] = (mi&&mj)? d*0.25f : NEG_INF_F;
      mx = fmaxf(mx,lgv[j]);
    }
    float sum=0.f, ex[5];
    #pragma unroll
    for (int j=0;j<5;j++){ ex[j]=__expf(lgv[j]-mx); sum+=ex[j]; }
    float inv=1.0f/sum;
    #pragma unroll
    for (int j=0;j<5;j++) ATTb[T*100+(h*5+i)*5+j]=(__bf16)(ex[j]*inv);
  }
  {
    int h = lane>>4;
    #pragma unroll
    for (int tg=0; tg<3; tg++){
      int T=3*wv+tg;
      float v5[5];
      #pragma unroll
      for (int j=0;j<5;j++) v5[j] = (float)Ab[(T*5+j)*136+64+lane];
      #pragma unroll
      for (int i=0;i<5;i++){
        float o=0.f;
        #pragma unroll
        for (int j=0;j<5;j++) o += (float)ATTb[T*100+(h*5+i)*5+j]*v5[j];
        Ab[(T*5+i)*136+lane]=(__bf16)o;
      }
    }
  }
  BAR();   // S3

  // ---- o-proj + residual -> Tk (col-slices) ----
  gemmW<2,4,1>(actAb, wfO, wv, lane,
    [&](int wb,int mt,int r,v4f c){
      int R=mt*16+r; float mm=(float)mfb[R];
      v4bf old=*(const v4bf*)&Tk[R*72+wb]; v4bf o;
      #pragma unroll
      for (int k=0;k<4;k++) o[k]=(__bf16)((float)old[k]+c[k]*mm);
      *(v4bf*)&Tk[R*72+wb]=o; });
  auto wfM1 = wload<2,2>(ws+W_M1, a.m1_b, wv, lane);    // survives S4+S5
  BAR();   // S4

  // ---- ln2 -> Ab[:,0:64] (own rows) ----
  if (ar<15){
    int R = 15*wv + ar;
    float x[16]; load16f(Tk + R*72 + quad*16, x);
    float s=0.f;
    #pragma unroll
    for (int i=0;i<16;i++) s += x[i];
    s += __shfl_xor(s,16,64); s += __shfl_xor(s,32,64);
    float m = s*(1.f/64.f), q=0.f;
    #pragma unroll
    for (int i=0;i<16;i++){ float d=x[i]-m; q=fmaf(d,d,q); }
    q += __shfl_xor(q,16,64); q += __shfl_xor(q,32,64);
    float rs = __builtin_amdgcn_rsqf(q*(1.f/64.f)+1e-6f);
    v8bf o0,o1;
    #pragma unroll
    for (int i=0;i<8;i++){
      o0[i]=(__bf16)((x[i]  -m)*rs*a.ln2_s[quad*16+i]  +a.ln2_b[quad*16+i]);
      o1[i]=(__bf16)((x[8+i]-m)*rs*a.ln2_s[quad*16+8+i]+a.ln2_b[quad*16+8+i]);
    }
    *(v8bf*)(Ab+R*136+quad*16)=o0; *(v8bf*)(Ab+R*136+quad*16+8)=o1;
  }
  BAR();   // S5

  // ---- m1 -> Bb[:,0:128] ----
  gemmW<2,4,2>(actAb, wfM1, wv, lane,
    [&](int wb,int mt,int r,v4f c){ v4bf o;
      #pragma unroll
      for (int k=0;k<4;k++) o[k]=(__bf16)gelu_f(c[k]);
      *(v4bf*)&Bb[(mt*16+r)*136+wb]=o; });
  auto wfM2 = wload<4,2>(ws+W_M2, a.m2_b, wv, lane);
  BAR();   // S6
  // ---- m2 -> Ab[:,0:128] ----
  gemmW<4,4,2>(actBb, wfM2, wv, lane,
    [&](int wb,int mt,int r,v4f c){ v4bf o;
      #pragma unroll
      for (int k=0;k<4;k++) o[k]=(__bf16)gelu_f(c[k]);
      *(v4bf*)&Ab[(mt*16+r)*136+wb]=o; });
  auto wfM3 = wload<4,1>(ws+W_M3, a.m3_b, wv, lane);
  auto wfE1 = wload<1,2>(ws+W_E1, a.e1_b, wv, lane);
  BAR();   // S7
  // ---- m3 -> Tk (resid*mask) ; e1 (token-level) -> Bb rows 0..15 ----
  gemmW<4,4,1>(actAb, wfM3, wv, lane,
    [&](int wb,int mt,int r,v4f c){
      int R=mt*16+r; float mm=(float)mfb[R];
      v4bf old=*(const v4bf*)&Tk[R*72+wb]; v4bf o;
      #pragma unroll
      for (int k=0;k<4;k++) o[k]=(__bf16)(((float)old[k]+c[k]*mm)*mm);
      *(v4bf*)&Tk[R*72+wb]=o; });
  gemmW<1,1,2>([&](int,int,int r,int q){ return *(const v8bf*)(Eg + (size_t)r*40 + q*8); },
    wfE1, wv, lane,
    [&](int wb,int mt,int r,v4f c){ v4bf o;
      #pragma unroll
      for (int k=0;k<4;k++) o[k]=(__bf16)gelu_f(c[k]);
      *(v4bf*)&Bb[r*136+wb]=o; });
  auto wfE2 = wload<4,2>(ws+W_E2, a.e2_b, wv, lane);
  BAR();   // S8
  // ---- e2 -> Ab rows 0..15 ----
  gemmW<4,1,2>(actBb, wfE2, wv, lane,
    [&](int wb,int mt,int r,v4f c){ v4bf o;
      #pragma unroll
      for (int k=0;k<4;k++) o[k]=(__bf16)gelu_f(c[k]);
      *(v4bf*)&Ab[r*136+wb]=o; });
  auto wfE3 = wload<4,1>(ws+W_E3, a.e3_b, wv, lane);
  BAR();   // S9
  // ---- e3 -> ECX rows 0..15 ----
  gemmW<4,1,1>(actAb, wfE3, wv, lane,
    [&](int wb,int mt,int r,v4f c){ v4bf o;
      #pragma unroll
      for (int k=0;k<4;k++) o[k]=(__bf16)c[k];
      *(v4bf*)&ECX[r*64+wb]=o; });
  auto wfL1 = wload<4,2>(ws+W_L1, a.l1_b, wv, lane);
  BAR();   // S10
  // ---- l1 (act = [Tk | ECX(token)]) -> Bb[:,0:128] ----
  gemmW<4,4,2>([&](int mt,int kt,int r,int q){
      int R=mt*16+r;
      return (kt<2) ? *(const v8bf*)(Tk + (size_t)R*72 + q*8 + kt*32)
                    : *(const v8bf*)(ECX + (size_t)((R*205)>>10)*64 + q*8 + (kt-2)*32); },
    wfL1, wv, lane,
    [&](int wb,int mt,int r,v4f c){ v4bf o;
      #pragma unroll
      for (int k=0;k<4;k++) o[k]=(__bf16)gelu_f(c[k]);
      *(v4bf*)&Bb[(mt*16+r)*136+wb]=o; });
  auto wfL2 = wload<4,2>(ws+W_L2, a.l2_b, wv, lane);
  BAR();   // S11
  // ---- l2 -> Ab[:,0:128] ----
  gemmW<4,4,2>(actBb, wfL2, wv, lane,
    [&](int wb,int mt,int r,v4f c){ v4bf o;
      #pragma unroll
      for (int k=0;k<4;k++) o[k]=(__bf16)gelu_f(c[k]);
      *(v4bf*)&Ab[(mt*16+r)*136+wb]=o; });
  auto wfPK = wload<2,1>(ws+W_PK, a.p_kb, wv, lane);
  auto wfPV = wload<2,1>(ws+W_PV, a.p_vb, wv, lane);
  BAR();   // S12

  // ---- l3 (own rows) + alpha + v_r/v_u ; kp/vp -> Bb ----
  if (ar<15){
    int R = 15*wv + ar;
    float x[16], y[16];
    load16f(&Ab[R*136 + quad*32], x);
    load16f(&Ab[R*136 + quad*32 + 16], y);
    const float* w = a.l3_w + quad*32;
    float p = 0.f;
    #pragma unroll
    for (int i=0;i<16;i++) p = fmaf(x[i], w[i], p);
    #pragma unroll
    for (int i=0;i<16;i++) p = fmaf(y[i], w[16+i], p);
    p += __shfl_xor(p,16,64); p += __shfl_xor(p,32,64);
    if (quad==0) lga[R] = p + a.l3_b[0];
  }
  gemmW<2,4,1>(actTk, wfPK, wv, lane,
    [&](int wb,int mt,int r,v4f c){ v4bf o;
      #pragma unroll
      for (int k=0;k<4;k++) o[k]=(__bf16)c[k];
      *(v4bf*)&Bb[(mt*16+r)*136+wb]=o; });
  gemmW<2,4,1>(actTk, wfPV, wv, lane,
    [&](int wb,int mt,int r,v4f c){ v4bf o;
      #pragma unroll
      for (int k=0;k<4;k++) o[k]=(__bf16)c[k];
      *(v4bf*)&Bb[(mt*16+r)*136+64+wb]=o; });
  if (lane<3){
    int T=3*wv+lane;
    float ml[5], mx=-1e9f;
    #pragma unroll
    for (int i=0;i<5;i++){ ml[i]=((float)mfb[T*5+i]>0.5f)? lga[T*5+i] : -1e9f; mx=fmaxf(mx,ml[i]); }
    float den=0.f, e[5];
    #pragma unroll
    for (int i=0;i<5;i++){ e[i]=__expf(ml[i]-mx)*(float)mfb[T*5+i]; den+=e[i]; }
    float inv=1.0f/(den+1e-9f);
    #pragma unroll
    for (int i=0;i<5;i++) lga[T*5+i]=e[i]*inv;
  }
  if (lane<18){
    int tg=lane/6, c=lane-tg*6;
    int T=3*wv+tg;
    float v=0.f;
    #pragma unroll
    for (int i=0;i<5;i++) v += lga[T*5+i]*(float)Ru[T*30+i*6+c];
    long tk = blkT0 + T;
    if (tk<ntok) a.out[tk*134+128+c]=v;
  }
  BAR();   // S13

  // ---- pooling attn + pooled-o (wave-local tokens) ----
  if (lane<12){
    const float* qg = (const float*)(ws + W_QP);
    int tg=lane>>2, h=lane&3;
    int T=3*wv+tg;
    float qv[16];
    #pragma unroll
    for (int dd=0;dd<16;dd++) qv[dd]=qg[h*16+dd];
    float lgv[5], mx=NEG_INF_F;
    #pragma unroll
    for (int j=0;j<5;j++){
      float kk[16]; load16f(&Bb[(T*5+j)*136 + h*16], kk);
      float d=0.f;
      #pragma unroll
      for (int dd=0;dd<16;dd++) d += qv[dd]*kk[dd];
      lgv[j] = ((float)msfb[T*5+j]>0.5f)? d*0.25f : NEG_INF_F;
      mx = fmaxf(mx,lgv[j]);
    }
    float sum=0.f, ex[5];
    #pragma unroll
    for (int j=0;j<5;j++){ ex[j]=__expf(lgv[j]-mx); sum+=ex[j]; }
    float inv=1.0f/sum;
    #pragma unroll
    for (int j=0;j<5;j++) pattn[T*20+h*5+j]=ex[j]*inv;
  }
  for (int it=lane; it<192; it+=64){
    int tg=it>>6, c=it&63, h=c>>4;
    int T=3*wv+tg;
    float o=0.f;
    #pragma unroll
    for (int j=0;j<5;j++)
      o += pattn[T*20+h*5+j]*(float)Bb[(T*5+j)*136+64+c];
    Po[T*64+c]=(__bf16)o;
  }
  auto wfPO = wload<2,1>(ws+W_PO, a.p_ob, wv, lane);
  BAR();   // S14

  // ---- p_ow -> Cc (x many) ----
  gemmW<2,1,1>([&](int,int kt,int r,int q){ return *(const v8bf*)(Po + (size_t)r*64 + q*8 + kt*32); },
    wfPO, wv, lane,
    [&](int wb,int mt,int r,v4f c){
      float mm = many[r];
      v4bf o;
      #pragma unroll
      for (int k=0;k<4;k++) o[k]=(__bf16)(c[k]*mm);
      *(v4bf*)&Cc[r*64+wb]=o; });
  auto wfH1 = wload<5,2>(ws+W_H1, a.h1_b, wv, lane);
  BAR();   // S15

  // ---- h1 (act = [Eg | Cc | Pe], K=160) -> Bb rows 0..15 ----
  gemmW<5,1,2>([&](int,int kt,int r,int q){
      if (kt==0) return *(const v8bf*)(Eg + (size_t)r*40 + q*8);
      if (kt<3)  return *(const v8bf*)(Cc + (size_t)r*64 + q*8 + (kt-1)*32);
      return *(const v8bf*)(Pe + (size_t)r*64 + q*8 + (kt-3)*32); },
    wfH1, wv, lane,
    [&](int wb,int mt,int r,v4f c){ v4bf o;
      #pragma unroll
      for (int k=0;k<4;k++) o[k]=(__bf16)gelu_f(c[k]);
      *(v4bf*)&Bb[r*136+wb]=o; });
  auto wfH2 = wload<4,2>(ws+W_H2, a.h2_b, wv, lane);
  BAR();   // S16
  // ---- h2 -> Ab rows 0..15 ----
  gemmW<4,1,2>(actBb, wfH2, wv, lane,
    [&](int wb,int mt,int r,v4f c){ v4bf o;
      #pragma unroll
      for (int k=0;k<4;k++) o[k]=(__bf16)gelu_f(c[k]);
      *(v4bf*)&Ab[r*136+wb]=o; });
  auto wfH3 = wload<4,2>(ws+W_H3, a.h3_b, wv, lane);
  BAR();   // S17
  // ---- h3 -> out ----
  gemmW<4,1,2>(actAb, wfH3, wv, lane,
    [&](int wb,int mt,int r,v4f c){
      long tk = blkT0 + r;
      if (r<12 && tk<ntok){
        float2* o2 = (float2*)&a.out[tk*134 + wb];
        o2[0] = make_float2(c[0], c[1]);
        o2[1] = make_float2(c[2], c[3]);
      } });
}

extern "C" void kernel_launch(void* const* d_in, const int* in_sizes, int n_in,
                              void* d_out, int out_size, void* d_ws, size_t ws_size,
                              hipStream_t stream)
{
  P a;
  const float** pp = reinterpret_cast<const float**>(&a);
  for (int i=0;i<50;i++) pp[i] = reinterpret_cast<const float*>(d_in[i]);
  a.out = reinterpret_cast<float*>(d_out);
  int ntok = in_sizes[0] / DOBS;   // 65536

  __bf16* ws = reinterpret_cast<__bf16*>(d_ws);
  hipLaunchKernelGGL(prep_w, dim3(173), dim3(256), 0, stream, a, ws);
  hipLaunchKernelGGL(swarm_mfma, dim3((ntok+11)/12), dim3(256), 0, stream, a, ws, ntok);
}